// Round 5
// baseline (617.300 us; speedup 1.0000x reference)
//
#include <hip/hip_runtime.h>

#define N_NODES 50000
#define N_EDGES 1600000
#define ND 16
#define ED 16
#define HID 64
#define M1 (2*ND+ED)   // 48
#define M2 (ND+ED)     // 32

// ---------------- count+slot: slot[idx] = count[dst]++  (all atomics isolated here)
__global__ __launch_bounds__(256) void count_slot_kernel(
    const int* __restrict__ ei,        // [2, E]
    unsigned* __restrict__ count,      // [N] zeroed
    unsigned short* __restrict__ slot) // [E]
{
    int idx = blockIdx.x * blockDim.x + threadIdx.x;
    if (idx >= N_EDGES) return;
    int dst = ei[N_EDGES + idx];
    slot[idx] = (unsigned short)atomicAdd(count + dst, 1u);
}

// ---------------- edge kernel: e_new = fR(concat(x[dst], x[src], e));  NO atomics
__global__ __launch_bounds__(256) void edge_kernel(
    const float* __restrict__ x,      // [N, 16]
    const int*   __restrict__ ei,     // [2, E]
    const float* __restrict__ e,      // [E, 16]
    const float* __restrict__ W1,     // [48, 64]
    const float* __restrict__ b1,     // [64]
    const float* __restrict__ W2,     // [64, 16]
    const float* __restrict__ b2,     // [16]
    float* __restrict__ e_new)        // [E, 16]
{
    int idx = blockIdx.x * blockDim.x + threadIdx.x;
    if (idx >= N_EDGES) return;
    int src = ei[idx];
    int dst = ei[N_EDGES + idx];

    float m[M1];
    {
        const float4* xd = reinterpret_cast<const float4*>(x) + dst * 4;
        const float4* xs = reinterpret_cast<const float4*>(x) + src * 4;
        const float4* ep = reinterpret_cast<const float4*>(e) + (size_t)idx * 4;
#pragma unroll
        for (int q = 0; q < 4; ++q) {
            float4 v = xd[q];
            m[4*q+0] = v.x; m[4*q+1] = v.y; m[4*q+2] = v.z; m[4*q+3] = v.w;
        }
#pragma unroll
        for (int q = 0; q < 4; ++q) {
            float4 v = xs[q];
            m[16+4*q+0] = v.x; m[16+4*q+1] = v.y; m[16+4*q+2] = v.z; m[16+4*q+3] = v.w;
        }
#pragma unroll
        for (int q = 0; q < 4; ++q) {
            float4 v = ep[q];
            m[32+4*q+0] = v.x; m[32+4*q+1] = v.y; m[32+4*q+2] = v.z; m[32+4*q+3] = v.w;
        }
    }

    float h[HID];
#pragma unroll
    for (int j = 0; j < HID; ++j) h[j] = b1[j];
#pragma unroll 4
    for (int i = 0; i < M1; ++i) {
        float mi = m[i];
        const float* wr = W1 + i * HID;
#pragma unroll
        for (int j = 0; j < HID; ++j) h[j] = fmaf(mi, wr[j], h[j]);
    }

    float o[ED];
#pragma unroll
    for (int k = 0; k < ED; ++k) o[k] = b2[k];
#pragma unroll 8
    for (int j = 0; j < HID; ++j) {
        float hj = fmaxf(h[j], 0.0f);
        const float* wr = W2 + j * ED;
#pragma unroll
        for (int k = 0; k < ED; ++k) o[k] = fmaf(hj, wr[k], o[k]);
    }

    float4* op = reinterpret_cast<float4*>(e_new) + (size_t)idx * 4;
    op[0] = make_float4(o[0], o[1], o[2],  o[3]);
    op[1] = make_float4(o[4], o[5], o[6],  o[7]);
    op[2] = make_float4(o[8], o[9], o[10], o[11]);
    op[3] = make_float4(o[12], o[13], o[14], o[15]);
}

// ---------------- single-block exclusive scan over count[N] -> offs[N+1]
__global__ __launch_bounds__(1024) void scan_kernel(
    const unsigned* __restrict__ count, unsigned* __restrict__ offs)
{
    __shared__ unsigned sums[1024];
    const int t = threadIdx.x;
    const int C = (N_NODES + 1023) / 1024;  // 49
    int lo = t * C;
    int hi = lo + C; if (hi > N_NODES) hi = N_NODES;
    unsigned s = 0;
    for (int i = lo; i < hi && i >= 0; ++i) s += count[i];
    sums[t] = s;
    __syncthreads();
    for (int d = 1; d < 1024; d <<= 1) {
        unsigned v = (t >= d) ? sums[t - d] : 0u;
        __syncthreads();
        sums[t] += v;
        __syncthreads();
    }
    unsigned run = (t == 0) ? 0u : sums[t - 1];
    for (int i = lo; i < hi && i >= 0; ++i) { offs[i] = run; run += count[i]; }
    if (t == 1023) offs[N_NODES] = run;
}

// ---------------- fill: elist[offs[dst] + slot[idx]] = idx (no atomics)
__global__ __launch_bounds__(256) void fill_kernel(
    const int* __restrict__ ei,
    const unsigned* __restrict__ offs,
    const unsigned short* __restrict__ slot,
    unsigned* __restrict__ elist)
{
    int idx = blockIdx.x * blockDim.x + threadIdx.x;
    if (idx >= N_EDGES) return;
    int dst = ei[N_EDGES + idx];
    elist[offs[dst] + (unsigned)slot[idx]] = (unsigned)idx;
}

// ---------------- agg: 4 threads per node, gather e_new rows and sum
__global__ __launch_bounds__(256) void agg_kernel(
    const float* __restrict__ e_new,   // [E,16]
    const unsigned* __restrict__ offs, // [N+1]
    const unsigned* __restrict__ count,// [N]
    const unsigned* __restrict__ elist,// [E]
    float* __restrict__ agg)           // [N,16]
{
    int tid = blockIdx.x * blockDim.x + threadIdx.x;
    if (tid >= N_NODES * 4) return;
    int n = tid >> 2;
    int q = tid & 3;
    unsigned base = offs[n];
    unsigned deg  = count[n];
    const float4* ep = reinterpret_cast<const float4*>(e_new);
    float4 s = make_float4(0.f, 0.f, 0.f, 0.f);
    for (unsigned j = 0; j < deg; ++j) {
        unsigned eid = elist[base + j];
        float4 v = ep[(size_t)eid * 4 + q];
        s.x += v.x; s.y += v.y; s.z += v.z; s.w += v.w;
    }
    reinterpret_cast<float4*>(agg)[(size_t)n * 4 + q] = s;
}

// ---------------- node kernel: x_new = fO(concat(x, agg))
__global__ __launch_bounds__(256) void node_kernel(
    const float* __restrict__ x,      // [N, 16]
    const float* __restrict__ agg,    // [N, 16]
    const float* __restrict__ W1,     // [32, 64]
    const float* __restrict__ b1,     // [64]
    const float* __restrict__ W2,     // [64, 16]
    const float* __restrict__ b2,     // [16]
    float* __restrict__ x_new)        // [N, 16]
{
    int idx = blockIdx.x * blockDim.x + threadIdx.x;
    if (idx >= N_NODES) return;

    float m[M2];
    {
        const float4* xp = reinterpret_cast<const float4*>(x) + idx * 4;
        const float4* ap = reinterpret_cast<const float4*>(agg) + idx * 4;
#pragma unroll
        for (int q = 0; q < 4; ++q) {
            float4 v = xp[q];
            m[4*q+0] = v.x; m[4*q+1] = v.y; m[4*q+2] = v.z; m[4*q+3] = v.w;
        }
#pragma unroll
        for (int q = 0; q < 4; ++q) {
            float4 v = ap[q];
            m[16+4*q+0] = v.x; m[16+4*q+1] = v.y; m[16+4*q+2] = v.z; m[16+4*q+3] = v.w;
        }
    }

    float h[HID];
#pragma unroll
    for (int j = 0; j < HID; ++j) h[j] = b1[j];
#pragma unroll 4
    for (int i = 0; i < M2; ++i) {
        float mi = m[i];
        const float* wr = W1 + i * HID;
#pragma unroll
        for (int j = 0; j < HID; ++j) h[j] = fmaf(mi, wr[j], h[j]);
    }

    float o[ED];
#pragma unroll
    for (int k = 0; k < ED; ++k) o[k] = b2[k];
#pragma unroll 8
    for (int j = 0; j < HID; ++j) {
        float hj = fmaxf(h[j], 0.0f);
        const float* wr = W2 + j * ED;
#pragma unroll
        for (int k = 0; k < ED; ++k) o[k] = fmaf(hj, wr[k], o[k]);
    }

    float4* op = reinterpret_cast<float4*>(x_new) + idx * 4;
    op[0] = make_float4(o[0], o[1], o[2],  o[3]);
    op[1] = make_float4(o[4], o[5], o[6],  o[7]);
    op[2] = make_float4(o[8], o[9], o[10], o[11]);
    op[3] = make_float4(o[12], o[13], o[14], o[15]);
}

// ---------------- legacy fallback (if ws too small): direct fp32 atomics
__global__ __launch_bounds__(256) void edge_kernel_atomic(
    const float* __restrict__ x, const int* __restrict__ ei,
    const float* __restrict__ e,
    const float* __restrict__ W1, const float* __restrict__ b1,
    const float* __restrict__ W2, const float* __restrict__ b2,
    float* __restrict__ e_new, float* __restrict__ agg)
{
    int idx = blockIdx.x * blockDim.x + threadIdx.x;
    if (idx >= N_EDGES) return;
    int src = ei[idx];
    int dst = ei[N_EDGES + idx];
    float m[M1];
    const float4* xd = reinterpret_cast<const float4*>(x) + dst * 4;
    const float4* xs = reinterpret_cast<const float4*>(x) + src * 4;
    const float4* ep = reinterpret_cast<const float4*>(e) + (size_t)idx * 4;
#pragma unroll
    for (int q = 0; q < 4; ++q) { float4 v = xd[q]; m[4*q]=v.x; m[4*q+1]=v.y; m[4*q+2]=v.z; m[4*q+3]=v.w; }
#pragma unroll
    for (int q = 0; q < 4; ++q) { float4 v = xs[q]; m[16+4*q]=v.x; m[16+4*q+1]=v.y; m[16+4*q+2]=v.z; m[16+4*q+3]=v.w; }
#pragma unroll
    for (int q = 0; q < 4; ++q) { float4 v = ep[q]; m[32+4*q]=v.x; m[32+4*q+1]=v.y; m[32+4*q+2]=v.z; m[32+4*q+3]=v.w; }
    float h[HID];
#pragma unroll
    for (int j = 0; j < HID; ++j) h[j] = b1[j];
#pragma unroll 4
    for (int i = 0; i < M1; ++i) {
        float mi = m[i]; const float* wr = W1 + i * HID;
#pragma unroll
        for (int j = 0; j < HID; ++j) h[j] = fmaf(mi, wr[j], h[j]);
    }
    float o[ED];
#pragma unroll
    for (int k = 0; k < ED; ++k) o[k] = b2[k];
#pragma unroll 8
    for (int j = 0; j < HID; ++j) {
        float hj = fmaxf(h[j], 0.0f); const float* wr = W2 + j * ED;
#pragma unroll
        for (int k = 0; k < ED; ++k) o[k] = fmaf(hj, wr[k], o[k]);
    }
    float4* op = reinterpret_cast<float4*>(e_new) + (size_t)idx * 4;
    op[0] = make_float4(o[0],o[1],o[2],o[3]);
    op[1] = make_float4(o[4],o[5],o[6],o[7]);
    op[2] = make_float4(o[8],o[9],o[10],o[11]);
    op[3] = make_float4(o[12],o[13],o[14],o[15]);
    float* ag = agg + (size_t)dst * ED;
#pragma unroll
    for (int k = 0; k < ED; ++k) atomicAdd(ag + k, o[k]);
}

static inline size_t align_up(size_t v, size_t a) { return (v + a - 1) / a * a; }

extern "C" void kernel_launch(void* const* d_in, const int* in_sizes, int n_in,
                              void* d_out, int out_size, void* d_ws, size_t ws_size,
                              hipStream_t stream) {
    const float* x     = (const float*)d_in[0];
    const int*   ei    = (const int*)  d_in[1];
    const float* e     = (const float*)d_in[2];
    const float* fR_W1 = (const float*)d_in[3];
    const float* fR_b1 = (const float*)d_in[4];
    const float* fR_W2 = (const float*)d_in[5];
    const float* fR_b2 = (const float*)d_in[6];
    const float* fO_W1 = (const float*)d_in[7];
    const float* fO_b1 = (const float*)d_in[8];
    const float* fO_W2 = (const float*)d_in[9];
    const float* fO_b2 = (const float*)d_in[10];

    float* x_new = (float*)d_out;                        // [N, 16]
    float* e_new = (float*)d_out + (size_t)N_NODES * ND; // [E, 16]

    char* ws = (char*)d_ws;
    size_t o = 0;
    unsigned*       count = (unsigned*)(ws + o);       o += align_up((size_t)N_NODES * 4, 256);
    unsigned*       offs  = (unsigned*)(ws + o);       o += align_up((size_t)(N_NODES + 1) * 4, 256);
    unsigned short* slot  = (unsigned short*)(ws + o); o += align_up((size_t)N_EDGES * 2, 256);
    unsigned*       elist = (unsigned*)(ws + o);       o += align_up((size_t)N_EDGES * 4, 256);
    float*          agg   = (float*)(ws + o);          o += align_up((size_t)N_NODES * ED * 4, 256);
    const size_t need = o;

    if (ws_size >= need) {
        hipMemsetAsync(count, 0, (size_t)N_NODES * 4, stream);
        // atomics isolated in a tiny kernel; edge MLP kernel is atomic-free
        count_slot_kernel<<<N_EDGES / 256, 256, 0, stream>>>(ei, count, slot);
        edge_kernel<<<N_EDGES / 256, 256, 0, stream>>>(
            x, ei, e, fR_W1, fR_b1, fR_W2, fR_b2, e_new);
        scan_kernel<<<1, 1024, 0, stream>>>(count, offs);
        fill_kernel<<<N_EDGES / 256, 256, 0, stream>>>(ei, offs, slot, elist);
        agg_kernel<<<(N_NODES * 4 + 255) / 256, 256, 0, stream>>>(
            e_new, offs, count, elist, agg);
        node_kernel<<<(N_NODES + 255) / 256, 256, 0, stream>>>(
            x, agg, fO_W1, fO_b1, fO_W2, fO_b2, x_new);
    } else {
        float* agg0 = (float*)d_ws;  // [N,16]
        hipMemsetAsync(agg0, 0, (size_t)N_NODES * ED * 4, stream);
        edge_kernel_atomic<<<N_EDGES / 256, 256, 0, stream>>>(
            x, ei, e, fR_W1, fR_b1, fR_W2, fR_b2, e_new, agg0);
        node_kernel<<<(N_NODES + 255) / 256, 256, 0, stream>>>(
            x, agg0, fO_W1, fO_b1, fO_W2, fO_b2, x_new);
    }
}

// Round 6
// 325.135 us; speedup vs baseline: 1.8986x; 1.8986x over previous
//
#include <hip/hip_runtime.h>
#include <hip/hip_bf16.h>

#define N_NODES 50000
#define N_EDGES 1600000
#define ND 16
#define ED 16
#define HID 64
#define M1 (2*ND+ED)   // 48
#define M2 (ND+ED)     // 32
#define N_TILES (N_EDGES / 16)   // 100000
#define WAVES 4
#define TILES_PER_WAVE 16

typedef short bf16x8 __attribute__((ext_vector_type(8)));
typedef float f32x4  __attribute__((ext_vector_type(4)));

__device__ inline unsigned pack_bf16(float a, float b) {
    __hip_bfloat162 p = __float22bfloat162_rn(float2{a, b});
    return *reinterpret_cast<unsigned*>(&p);
}

// ---------------- count+slot: slot[idx] = count[dst]++
__global__ __launch_bounds__(256) void count_slot_kernel(
    const int* __restrict__ ei, unsigned* __restrict__ count,
    unsigned short* __restrict__ slot)
{
    int idx = blockIdx.x * blockDim.x + threadIdx.x;
    if (idx >= N_EDGES) return;
    int dst = ei[N_EDGES + idx];
    slot[idx] = (unsigned short)atomicAdd(count + dst, 1u);
}

// ---------------- MFMA edge kernel: e_new = fR(concat(x[dst], x[src], e))
// One wave = 16 edges/tile. Weights live in registers as B-fragments.
// LDS per wave: m-rows [16][128B bf16] + h-rows [16][256B f32], XOR-swizzled.
__global__ __launch_bounds__(256) void edge_mfma_kernel(
    const float* __restrict__ x,      // [N, 16]
    const int*   __restrict__ ei,     // [2, E]
    const float* __restrict__ e,      // [E, 16]
    const float* __restrict__ W1,     // [48, 64]
    const float* __restrict__ b1,     // [64]
    const float* __restrict__ W2,     // [64, 16]
    const float* __restrict__ b2,     // [16]
    float* __restrict__ e_new)        // [E, 16]
{
    __shared__ __align__(16) char lds[WAVES * (2048 + 4096)];
    const int lane  = threadIdx.x & 63;
    const int wave  = threadIdx.x >> 6;
    char* mbase = lds + wave * 2048;                  // [16 rows][128 B] bf16
    char* hbase = lds + WAVES * 2048 + wave * 4096;   // [16 rows][256 B] f32

    const int row16 = lane & 15;   // M/N index within fragment
    const int kg    = lane >> 4;   // K-group 0..3

    // ---- preload weight fragments (B-layout: col=lane&15, k=kg*8+j) ----
    bf16x8 w1f[4][2];
#pragma unroll
    for (int t = 0; t < 4; ++t)
#pragma unroll
        for (int s = 0; s < 2; ++s) {
            union { bf16x8 v; unsigned u[4]; } fr;
#pragma unroll
            for (int r = 0; r < 4; ++r) {
                int k0 = s * 32 + kg * 8 + 2 * r;
                int n  = t * 16 + row16;
                float a = (k0     < M1) ? W1[k0 * HID + n]       : 0.f;
                float b = (k0 + 1 < M1) ? W1[(k0 + 1) * HID + n] : 0.f;
                fr.u[r] = pack_bf16(a, b);
            }
            w1f[t][s] = fr.v;
        }
    bf16x8 w2f[2];
#pragma unroll
    for (int s = 0; s < 2; ++s) {
        union { bf16x8 v; unsigned u[4]; } fr;
#pragma unroll
        for (int r = 0; r < 4; ++r) {
            int k0 = s * 32 + kg * 8 + 2 * r;
            fr.u[r] = pack_bf16(W2[k0 * ED + row16], W2[(k0 + 1) * ED + row16]);
        }
        w2f[s] = fr.v;
    }
    float b1v[4];
#pragma unroll
    for (int t = 0; t < 4; ++t) b1v[t] = b1[t * 16 + row16];
    const float b2v = b2[row16];

    const int erow = lane >> 2;  // staging: edge 0..15 within tile
    const int q    = lane & 3;   // staging: quarter 0..3

    // zero the K-pad (bf16 cols 48..63) once; never overwritten by tiles
    {
        unsigned off = ((unsigned)erow * 128 + 96 + q * 8) ^ (((unsigned)erow & 7) << 4);
        *(unsigned long long*)(mbase + off) = 0ull;
    }

    const int wtile0 = ((int)blockIdx.x * WAVES + wave) * TILES_PER_WAVE;

    for (int t = 0; t < TILES_PER_WAVE; ++t) {
        int tile = wtile0 + t;
        if (tile >= N_TILES) break;
        int ebase = tile * 16;
        int eidx  = ebase + erow;
        int src = ei[eidx];
        int dst = ei[N_EDGES + eidx];

        // ---- stage m row = [x[dst] | x[src] | e] as bf16 (swizzled) ----
        const float4 vd = reinterpret_cast<const float4*>(x)[dst * 4 + q];
        const float4 vs = reinterpret_cast<const float4*>(x)[src * 4 + q];
        const float4 ve = reinterpret_cast<const float4*>(e)[(size_t)eidx * 4 + q];
        const unsigned swz = ((unsigned)erow & 7) << 4;
        {
            unsigned off = ((unsigned)erow * 128 + 0 * 32 + q * 8) ^ swz;
            unsigned lo = pack_bf16(vd.x, vd.y), hi = pack_bf16(vd.z, vd.w);
            *(unsigned long long*)(mbase + off) = ((unsigned long long)hi << 32) | lo;
        }
        {
            unsigned off = ((unsigned)erow * 128 + 1 * 32 + q * 8) ^ swz;
            unsigned lo = pack_bf16(vs.x, vs.y), hi = pack_bf16(vs.z, vs.w);
            *(unsigned long long*)(mbase + off) = ((unsigned long long)hi << 32) | lo;
        }
        {
            unsigned off = ((unsigned)erow * 128 + 2 * 32 + q * 8) ^ swz;
            unsigned lo = pack_bf16(ve.x, ve.y), hi = pack_bf16(ve.z, ve.w);
            *(unsigned long long*)(mbase + off) = ((unsigned long long)hi << 32) | lo;
        }

        // ---- layer 1: A-frags (row=lane&15, k=kg*8+j) ----
        const unsigned asw = ((unsigned)row16 & 7) << 4;
        bf16x8 a0 = *(bf16x8*)(mbase + (((unsigned)row16 * 128 +  0 + kg * 16) ^ asw));
        bf16x8 a1 = *(bf16x8*)(mbase + (((unsigned)row16 * 128 + 64 + kg * 16) ^ asw));

        f32x4 acc[4];
#pragma unroll
        for (int tt = 0; tt < 4; ++tt) {
            acc[tt] = (f32x4){0.f, 0.f, 0.f, 0.f};
            acc[tt] = __builtin_amdgcn_mfma_f32_16x16x32_bf16(a0, w1f[tt][0], acc[tt], 0, 0, 0);
            acc[tt] = __builtin_amdgcn_mfma_f32_16x16x32_bf16(a1, w1f[tt][1], acc[tt], 0, 0, 0);
        }

        // ---- h = relu(acc + b1) -> h_lds f32 [16][64] (swizzled) ----
#pragma unroll
        for (int tt = 0; tt < 4; ++tt) {
#pragma unroll
            for (int r = 0; r < 4; ++r) {
                float hv = fmaxf(acc[tt][r] + b1v[tt], 0.f);
                unsigned hrow = (unsigned)(kg * 4 + r);
                unsigned off = (hrow * 256 + (unsigned)(tt * 16 + row16) * 4) ^ ((hrow & 7) << 4);
                *(float*)(hbase + off) = hv;
            }
        }

        // ---- layer 2: A2-frags from h (row=lane&15, k=s*32+kg*8+j) ----
        bf16x8 a2[2];
#pragma unroll
        for (int s = 0; s < 2; ++s) {
            unsigned base = (unsigned)row16 * 256 + s * 128 + kg * 32;
            f32x4 lo = *(f32x4*)(hbase + ((base +  0) ^ asw));
            f32x4 hi = *(f32x4*)(hbase + ((base + 16) ^ asw));
            union { bf16x8 v; unsigned u[4]; } fr;
            fr.u[0] = pack_bf16(lo[0], lo[1]);
            fr.u[1] = pack_bf16(lo[2], lo[3]);
            fr.u[2] = pack_bf16(hi[0], hi[1]);
            fr.u[3] = pack_bf16(hi[2], hi[3]);
            a2[s] = fr.v;
        }

        f32x4 oacc = (f32x4){0.f, 0.f, 0.f, 0.f};
        oacc = __builtin_amdgcn_mfma_f32_16x16x32_bf16(a2[0], w2f[0], oacc, 0, 0, 0);
        oacc = __builtin_amdgcn_mfma_f32_16x16x32_bf16(a2[1], w2f[1], oacc, 0, 0, 0);

        // ---- store e_new: C-layout row=(kg*4+r)=edge, col=row16=dim ----
#pragma unroll
        for (int r = 0; r < 4; ++r) {
            e_new[(size_t)(ebase + kg * 4 + r) * 16 + row16] = oacc[r] + b2v;
        }
    }
}

// ---------------- single-block exclusive scan over count[N] -> offs[N+1]
__global__ __launch_bounds__(1024) void scan_kernel(
    const unsigned* __restrict__ count, unsigned* __restrict__ offs)
{
    __shared__ unsigned sums[1024];
    const int t = threadIdx.x;
    const int C = (N_NODES + 1023) / 1024;
    int lo = t * C;
    int hi = lo + C; if (hi > N_NODES) hi = N_NODES;
    unsigned s = 0;
    for (int i = lo; i < hi && i >= 0; ++i) s += count[i];
    sums[t] = s;
    __syncthreads();
    for (int d = 1; d < 1024; d <<= 1) {
        unsigned v = (t >= d) ? sums[t - d] : 0u;
        __syncthreads();
        sums[t] += v;
        __syncthreads();
    }
    unsigned run = (t == 0) ? 0u : sums[t - 1];
    for (int i = lo; i < hi && i >= 0; ++i) { offs[i] = run; run += count[i]; }
    if (t == 1023) offs[N_NODES] = run;
}

// ---------------- fill: elist[offs[dst] + slot[idx]] = idx
__global__ __launch_bounds__(256) void fill_kernel(
    const int* __restrict__ ei, const unsigned* __restrict__ offs,
    const unsigned short* __restrict__ slot, unsigned* __restrict__ elist)
{
    int idx = blockIdx.x * blockDim.x + threadIdx.x;
    if (idx >= N_EDGES) return;
    int dst = ei[N_EDGES + idx];
    elist[offs[dst] + (unsigned)slot[idx]] = (unsigned)idx;
}

// ---------------- agg: 4 threads per node, gather e_new rows and sum
__global__ __launch_bounds__(256) void agg_kernel(
    const float* __restrict__ e_new, const unsigned* __restrict__ offs,
    const unsigned* __restrict__ count, const unsigned* __restrict__ elist,
    float* __restrict__ agg)
{
    int tid = blockIdx.x * blockDim.x + threadIdx.x;
    if (tid >= N_NODES * 4) return;
    int n = tid >> 2;
    int q = tid & 3;
    unsigned base = offs[n];
    unsigned deg  = count[n];
    const float4* ep = reinterpret_cast<const float4*>(e_new);
    float4 s = make_float4(0.f, 0.f, 0.f, 0.f);
    for (unsigned j = 0; j < deg; ++j) {
        unsigned eid = elist[base + j];
        float4 v = ep[(size_t)eid * 4 + q];
        s.x += v.x; s.y += v.y; s.z += v.z; s.w += v.w;
    }
    reinterpret_cast<float4*>(agg)[(size_t)n * 4 + q] = s;
}

// ---------------- node kernel: x_new = fO(concat(x, agg)) (fp32)
__global__ __launch_bounds__(256) void node_kernel(
    const float* __restrict__ x, const float* __restrict__ agg,
    const float* __restrict__ W1, const float* __restrict__ b1,
    const float* __restrict__ W2, const float* __restrict__ b2,
    float* __restrict__ x_new)
{
    int idx = blockIdx.x * blockDim.x + threadIdx.x;
    if (idx >= N_NODES) return;

    float m[M2];
    {
        const float4* xp = reinterpret_cast<const float4*>(x) + idx * 4;
        const float4* ap = reinterpret_cast<const float4*>(agg) + idx * 4;
#pragma unroll
        for (int q = 0; q < 4; ++q) {
            float4 v = xp[q];
            m[4*q+0] = v.x; m[4*q+1] = v.y; m[4*q+2] = v.z; m[4*q+3] = v.w;
        }
#pragma unroll
        for (int q = 0; q < 4; ++q) {
            float4 v = ap[q];
            m[16+4*q+0] = v.x; m[16+4*q+1] = v.y; m[16+4*q+2] = v.z; m[16+4*q+3] = v.w;
        }
    }

    float h[HID];
#pragma unroll
    for (int j = 0; j < HID; ++j) h[j] = b1[j];
#pragma unroll 4
    for (int i = 0; i < M2; ++i) {
        float mi = m[i];
        const float* wr = W1 + i * HID;
#pragma unroll
        for (int j = 0; j < HID; ++j) h[j] = fmaf(mi, wr[j], h[j]);
    }

    float o[ED];
#pragma unroll
    for (int k = 0; k < ED; ++k) o[k] = b2[k];
#pragma unroll 8
    for (int j = 0; j < HID; ++j) {
        float hj = fmaxf(h[j], 0.0f);
        const float* wr = W2 + j * ED;
#pragma unroll
        for (int k = 0; k < ED; ++k) o[k] = fmaf(hj, wr[k], o[k]);
    }

    float4* op = reinterpret_cast<float4*>(x_new) + idx * 4;
    op[0] = make_float4(o[0], o[1], o[2],  o[3]);
    op[1] = make_float4(o[4], o[5], o[6],  o[7]);
    op[2] = make_float4(o[8], o[9], o[10], o[11]);
    op[3] = make_float4(o[12], o[13], o[14], o[15]);
}

// ---------------- legacy fallback (if ws too small): direct fp32 atomics
__global__ __launch_bounds__(256) void edge_kernel_atomic(
    const float* __restrict__ x, const int* __restrict__ ei,
    const float* __restrict__ e,
    const float* __restrict__ W1, const float* __restrict__ b1,
    const float* __restrict__ W2, const float* __restrict__ b2,
    float* __restrict__ e_new, float* __restrict__ agg)
{
    int idx = blockIdx.x * blockDim.x + threadIdx.x;
    if (idx >= N_EDGES) return;
    int src = ei[idx];
    int dst = ei[N_EDGES + idx];
    float m[M1];
    const float4* xd = reinterpret_cast<const float4*>(x) + dst * 4;
    const float4* xs = reinterpret_cast<const float4*>(x) + src * 4;
    const float4* ep = reinterpret_cast<const float4*>(e) + (size_t)idx * 4;
#pragma unroll
    for (int q = 0; q < 4; ++q) { float4 v = xd[q]; m[4*q]=v.x; m[4*q+1]=v.y; m[4*q+2]=v.z; m[4*q+3]=v.w; }
#pragma unroll
    for (int q = 0; q < 4; ++q) { float4 v = xs[q]; m[16+4*q]=v.x; m[16+4*q+1]=v.y; m[16+4*q+2]=v.z; m[16+4*q+3]=v.w; }
#pragma unroll
    for (int q = 0; q < 4; ++q) { float4 v = ep[q]; m[32+4*q]=v.x; m[32+4*q+1]=v.y; m[32+4*q+2]=v.z; m[32+4*q+3]=v.w; }
    float h[HID];
#pragma unroll
    for (int j = 0; j < HID; ++j) h[j] = b1[j];
#pragma unroll 4
    for (int i = 0; i < M1; ++i) {
        float mi = m[i]; const float* wr = W1 + i * HID;
#pragma unroll
        for (int j = 0; j < HID; ++j) h[j] = fmaf(mi, wr[j], h[j]);
    }
    float o[ED];
#pragma unroll
    for (int k = 0; k < ED; ++k) o[k] = b2[k];
#pragma unroll 8
    for (int j = 0; j < HID; ++j) {
        float hj = fmaxf(h[j], 0.0f); const float* wr = W2 + j * ED;
#pragma unroll
        for (int k = 0; k < ED; ++k) o[k] = fmaf(hj, wr[k], o[k]);
    }
    float4* op = reinterpret_cast<float4*>(e_new) + (size_t)idx * 4;
    op[0] = make_float4(o[0],o[1],o[2],o[3]);
    op[1] = make_float4(o[4],o[5],o[6],o[7]);
    op[2] = make_float4(o[8],o[9],o[10],o[11]);
    op[3] = make_float4(o[12],o[13],o[14],o[15]);
    float* ag = agg + (size_t)dst * ED;
#pragma unroll
    for (int k = 0; k < ED; ++k) atomicAdd(ag + k, o[k]);
}

static inline size_t align_up(size_t v, size_t a) { return (v + a - 1) / a * a; }

extern "C" void kernel_launch(void* const* d_in, const int* in_sizes, int n_in,
                              void* d_out, int out_size, void* d_ws, size_t ws_size,
                              hipStream_t stream) {
    const float* x     = (const float*)d_in[0];
    const int*   ei    = (const int*)  d_in[1];
    const float* e     = (const float*)d_in[2];
    const float* fR_W1 = (const float*)d_in[3];
    const float* fR_b1 = (const float*)d_in[4];
    const float* fR_W2 = (const float*)d_in[5];
    const float* fR_b2 = (const float*)d_in[6];
    const float* fO_W1 = (const float*)d_in[7];
    const float* fO_b1 = (const float*)d_in[8];
    const float* fO_W2 = (const float*)d_in[9];
    const float* fO_b2 = (const float*)d_in[10];

    float* x_new = (float*)d_out;                        // [N, 16]
    float* e_new = (float*)d_out + (size_t)N_NODES * ND; // [E, 16]

    char* ws = (char*)d_ws;
    size_t o = 0;
    unsigned*       count = (unsigned*)(ws + o);       o += align_up((size_t)N_NODES * 4, 256);
    unsigned*       offs  = (unsigned*)(ws + o);       o += align_up((size_t)(N_NODES + 1) * 4, 256);
    unsigned short* slot  = (unsigned short*)(ws + o); o += align_up((size_t)N_EDGES * 2, 256);
    unsigned*       elist = (unsigned*)(ws + o);       o += align_up((size_t)N_EDGES * 4, 256);
    float*          agg   = (float*)(ws + o);          o += align_up((size_t)N_NODES * ED * 4, 256);
    const size_t need = o;

    if (ws_size >= need) {
        hipMemsetAsync(count, 0, (size_t)N_NODES * 4, stream);
        count_slot_kernel<<<N_EDGES / 256, 256, 0, stream>>>(ei, count, slot);

        const int tiles_per_block = WAVES * TILES_PER_WAVE;  // 64
        const int nblocks = (N_TILES + tiles_per_block - 1) / tiles_per_block;
        edge_mfma_kernel<<<nblocks, 256, 0, stream>>>(
            x, ei, e, fR_W1, fR_b1, fR_W2, fR_b2, e_new);

        scan_kernel<<<1, 1024, 0, stream>>>(count, offs);
        fill_kernel<<<N_EDGES / 256, 256, 0, stream>>>(ei, offs, slot, elist);
        agg_kernel<<<(N_NODES * 4 + 255) / 256, 256, 0, stream>>>(
            e_new, offs, count, elist, agg);
        node_kernel<<<(N_NODES + 255) / 256, 256, 0, stream>>>(
            x, agg, fO_W1, fO_b1, fO_W2, fO_b2, x_new);
    } else {
        float* agg0 = (float*)d_ws;
        hipMemsetAsync(agg0, 0, (size_t)N_NODES * ED * 4, stream);
        edge_kernel_atomic<<<N_EDGES / 256, 256, 0, stream>>>(
            x, ei, e, fR_W1, fR_b1, fR_W2, fR_b2, e_new, agg0);
        node_kernel<<<(N_NODES + 255) / 256, 256, 0, stream>>>(
            x, agg0, fO_W1, fO_b1, fO_W2, fO_b2, x_new);
    }
}

// Round 7
// 282.791 us; speedup vs baseline: 2.1829x; 1.1497x over previous
//
#include <hip/hip_runtime.h>
#include <hip/hip_bf16.h>

#define N_NODES 50000
#define N_EDGES 1600000
#define ND 16
#define ED 16
#define HID 64
#define M1 (2*ND+ED)   // 48
#define M2 (ND+ED)     // 32
#define N_TILES (N_EDGES / 16)   // 100000
#define WAVES 4
#define TILES_PER_WAVE 16

// CSR-build geometry
#define NB 128
#define CHUNK (N_EDGES / NB)     // 12500
#define NWORDS (N_NODES / 4)     // 12500 packed-u8 histogram words

typedef short bf16x8 __attribute__((ext_vector_type(8)));
typedef float f32x4  __attribute__((ext_vector_type(4)));

__device__ inline unsigned pack_bf16(float a, float b) {
    __hip_bfloat162 p = __float22bfloat162_rn(float2{a, b});
    return *reinterpret_cast<unsigned*>(&p);
}

// ---------------- hist: per-block LDS histogram (u8 x4 packed) + local slot
__global__ __launch_bounds__(1024) void hist_kernel(
    const int* __restrict__ ei,          // [2, E]
    unsigned* __restrict__ partial_w,    // [NB][NWORDS] packed u8 counts
    unsigned char* __restrict__ slot8)   // [E] local slot within (block, node)
{
    __shared__ unsigned hist[NWORDS];    // 50 KB
    const int b = blockIdx.x, t = threadIdx.x;
    for (int w = t; w < NWORDS; w += 1024) hist[w] = 0u;
    __syncthreads();
    const int base = b * CHUNK;
    for (int i = t; i < CHUNK; i += 1024) {
        int idx = base + i;
        int dst = ei[N_EDGES + idx];
        unsigned sh = (unsigned)(dst & 3) * 8u;
        unsigned old = atomicAdd(&hist[dst >> 2], 1u << sh);
        slot8[idx] = (unsigned char)((old >> sh) & 0xffu);
    }
    __syncthreads();
    unsigned* out = partial_w + (size_t)b * NWORDS;
    for (int w = t; w < NWORDS; w += 1024) out[w] = hist[w];
}

// ---------------- bprefix: in-place exclusive prefix over blocks per node
// partial_w[b][w] (counts) -> becomes bp[b][w] (packed u8 exclusive prefixes)
// count[n] = total degree
__global__ __launch_bounds__(256) void bprefix_kernel(
    unsigned* __restrict__ partial_w, unsigned* __restrict__ count)
{
    int w = blockIdx.x * blockDim.x + threadIdx.x;
    if (w >= NWORDS) return;
    unsigned r0 = 0, r1 = 0, r2 = 0, r3 = 0;
    for (int b = 0; b < NB; ++b) {
        size_t o = (size_t)b * NWORDS + w;
        unsigned v = partial_w[o];
        partial_w[o] = (r0 & 0xff) | ((r1 & 0xff) << 8) |
                       ((r2 & 0xff) << 16) | ((r3 & 0xff) << 24);
        r0 += v & 0xffu; r1 += (v >> 8) & 0xffu;
        r2 += (v >> 16) & 0xffu; r3 += (v >> 24) & 0xffu;
    }
    count[w * 4 + 0] = r0; count[w * 4 + 1] = r1;
    count[w * 4 + 2] = r2; count[w * 4 + 3] = r3;
}

// ---------------- single-block exclusive scan over count[N] -> offs[N+1]
__global__ __launch_bounds__(1024) void scan_kernel(
    const unsigned* __restrict__ count, unsigned* __restrict__ offs)
{
    __shared__ unsigned sums[1024];
    const int t = threadIdx.x;
    const int C = (N_NODES + 1023) / 1024;
    int lo = t * C;
    int hi = lo + C; if (hi > N_NODES) hi = N_NODES;
    unsigned s = 0;
    for (int i = lo; i < hi && i >= 0; ++i) s += count[i];
    sums[t] = s;
    __syncthreads();
    for (int d = 1; d < 1024; d <<= 1) {
        unsigned v = (t >= d) ? sums[t - d] : 0u;
        __syncthreads();
        sums[t] += v;
        __syncthreads();
    }
    unsigned run = (t == 0) ? 0u : sums[t - 1];
    for (int i = lo; i < hi && i >= 0; ++i) { offs[i] = run; run += count[i]; }
    if (t == 1023) offs[N_NODES] = run;
}

// ---------------- fill2: elist[offs[dst] + bp[b][dst] + slot8[idx]] = idx (atomic-free)
__global__ __launch_bounds__(1024) void fill2_kernel(
    const int* __restrict__ ei, const unsigned* __restrict__ offs,
    const unsigned* __restrict__ bp_w,     // [NB][NWORDS] packed u8 prefixes
    const unsigned char* __restrict__ slot8,
    unsigned* __restrict__ elist)
{
    const int b = blockIdx.x, t = threadIdx.x;
    const int base = b * CHUNK;
    const unsigned* bpb = bp_w + (size_t)b * NWORDS;
    for (int i = t; i < CHUNK; i += 1024) {
        int idx = base + i;
        int dst = ei[N_EDGES + idx];
        unsigned pre = (bpb[dst >> 2] >> ((unsigned)(dst & 3) * 8u)) & 0xffu;
        unsigned pos = offs[dst] + pre + (unsigned)slot8[idx];
        elist[pos] = (unsigned)idx;
    }
}

// ---------------- MFMA edge kernel (unchanged from round 6)
__global__ __launch_bounds__(256) void edge_mfma_kernel(
    const float* __restrict__ x, const int* __restrict__ ei,
    const float* __restrict__ e,
    const float* __restrict__ W1, const float* __restrict__ b1,
    const float* __restrict__ W2, const float* __restrict__ b2,
    float* __restrict__ e_new)
{
    __shared__ __align__(16) char lds[WAVES * (2048 + 4096)];
    const int lane  = threadIdx.x & 63;
    const int wave  = threadIdx.x >> 6;
    char* mbase = lds + wave * 2048;
    char* hbase = lds + WAVES * 2048 + wave * 4096;

    const int row16 = lane & 15;
    const int kg    = lane >> 4;

    bf16x8 w1f[4][2];
#pragma unroll
    for (int t = 0; t < 4; ++t)
#pragma unroll
        for (int s = 0; s < 2; ++s) {
            union { bf16x8 v; unsigned u[4]; } fr;
#pragma unroll
            for (int r = 0; r < 4; ++r) {
                int k0 = s * 32 + kg * 8 + 2 * r;
                int n  = t * 16 + row16;
                float a = (k0     < M1) ? W1[k0 * HID + n]       : 0.f;
                float b = (k0 + 1 < M1) ? W1[(k0 + 1) * HID + n] : 0.f;
                fr.u[r] = pack_bf16(a, b);
            }
            w1f[t][s] = fr.v;
        }
    bf16x8 w2f[2];
#pragma unroll
    for (int s = 0; s < 2; ++s) {
        union { bf16x8 v; unsigned u[4]; } fr;
#pragma unroll
        for (int r = 0; r < 4; ++r) {
            int k0 = s * 32 + kg * 8 + 2 * r;
            fr.u[r] = pack_bf16(W2[k0 * ED + row16], W2[(k0 + 1) * ED + row16]);
        }
        w2f[s] = fr.v;
    }
    float b1v[4];
#pragma unroll
    for (int t = 0; t < 4; ++t) b1v[t] = b1[t * 16 + row16];
    const float b2v = b2[row16];

    const int erow = lane >> 2;
    const int q    = lane & 3;

    {
        unsigned off = ((unsigned)erow * 128 + 96 + q * 8) ^ (((unsigned)erow & 7) << 4);
        *(unsigned long long*)(mbase + off) = 0ull;
    }

    const int wtile0 = ((int)blockIdx.x * WAVES + wave) * TILES_PER_WAVE;

    for (int t = 0; t < TILES_PER_WAVE; ++t) {
        int tile = wtile0 + t;
        if (tile >= N_TILES) break;
        int ebase = tile * 16;
        int eidx  = ebase + erow;
        int src = ei[eidx];
        int dst = ei[N_EDGES + eidx];

        const float4 vd = reinterpret_cast<const float4*>(x)[dst * 4 + q];
        const float4 vs = reinterpret_cast<const float4*>(x)[src * 4 + q];
        const float4 ve = reinterpret_cast<const float4*>(e)[(size_t)eidx * 4 + q];
        const unsigned swz = ((unsigned)erow & 7) << 4;
        {
            unsigned off = ((unsigned)erow * 128 + 0 * 32 + q * 8) ^ swz;
            unsigned lo = pack_bf16(vd.x, vd.y), hi = pack_bf16(vd.z, vd.w);
            *(unsigned long long*)(mbase + off) = ((unsigned long long)hi << 32) | lo;
        }
        {
            unsigned off = ((unsigned)erow * 128 + 1 * 32 + q * 8) ^ swz;
            unsigned lo = pack_bf16(vs.x, vs.y), hi = pack_bf16(vs.z, vs.w);
            *(unsigned long long*)(mbase + off) = ((unsigned long long)hi << 32) | lo;
        }
        {
            unsigned off = ((unsigned)erow * 128 + 2 * 32 + q * 8) ^ swz;
            unsigned lo = pack_bf16(ve.x, ve.y), hi = pack_bf16(ve.z, ve.w);
            *(unsigned long long*)(mbase + off) = ((unsigned long long)hi << 32) | lo;
        }

        const unsigned asw = ((unsigned)row16 & 7) << 4;
        bf16x8 a0 = *(bf16x8*)(mbase + (((unsigned)row16 * 128 +  0 + kg * 16) ^ asw));
        bf16x8 a1 = *(bf16x8*)(mbase + (((unsigned)row16 * 128 + 64 + kg * 16) ^ asw));

        f32x4 acc[4];
#pragma unroll
        for (int tt = 0; tt < 4; ++tt) {
            acc[tt] = (f32x4){0.f, 0.f, 0.f, 0.f};
            acc[tt] = __builtin_amdgcn_mfma_f32_16x16x32_bf16(a0, w1f[tt][0], acc[tt], 0, 0, 0);
            acc[tt] = __builtin_amdgcn_mfma_f32_16x16x32_bf16(a1, w1f[tt][1], acc[tt], 0, 0, 0);
        }

#pragma unroll
        for (int tt = 0; tt < 4; ++tt) {
#pragma unroll
            for (int r = 0; r < 4; ++r) {
                float hv = fmaxf(acc[tt][r] + b1v[tt], 0.f);
                unsigned hrow = (unsigned)(kg * 4 + r);
                unsigned off = (hrow * 256 + (unsigned)(tt * 16 + row16) * 4) ^ ((hrow & 7) << 4);
                *(float*)(hbase + off) = hv;
            }
        }

        bf16x8 a2[2];
#pragma unroll
        for (int s = 0; s < 2; ++s) {
            unsigned base = (unsigned)row16 * 256 + s * 128 + kg * 32;
            f32x4 lo = *(f32x4*)(hbase + ((base +  0) ^ asw));
            f32x4 hi = *(f32x4*)(hbase + ((base + 16) ^ asw));
            union { bf16x8 v; unsigned u[4]; } fr;
            fr.u[0] = pack_bf16(lo[0], lo[1]);
            fr.u[1] = pack_bf16(lo[2], lo[3]);
            fr.u[2] = pack_bf16(hi[0], hi[1]);
            fr.u[3] = pack_bf16(hi[2], hi[3]);
            a2[s] = fr.v;
        }

        f32x4 oacc = (f32x4){0.f, 0.f, 0.f, 0.f};
        oacc = __builtin_amdgcn_mfma_f32_16x16x32_bf16(a2[0], w2f[0], oacc, 0, 0, 0);
        oacc = __builtin_amdgcn_mfma_f32_16x16x32_bf16(a2[1], w2f[1], oacc, 0, 0, 0);

#pragma unroll
        for (int r = 0; r < 4; ++r) {
            e_new[(size_t)(ebase + kg * 4 + r) * 16 + row16] = oacc[r] + b2v;
        }
    }
}

// ---------------- fused agg + node MLP: 1 thread per node
__global__ __launch_bounds__(256) void agg_node_kernel(
    const float* __restrict__ e_new,   // [E,16]
    const unsigned* __restrict__ offs, // [N+1]
    const unsigned* __restrict__ elist,// [E]
    const float* __restrict__ x,       // [N,16]
    const float* __restrict__ W1, const float* __restrict__ b1,
    const float* __restrict__ W2, const float* __restrict__ b2,
    float* __restrict__ x_new)         // [N,16]
{
    int n = blockIdx.x * blockDim.x + threadIdx.x;
    if (n >= N_NODES) return;

    float m[M2];
    {
        const float4* xp = reinterpret_cast<const float4*>(x) + n * 4;
#pragma unroll
        for (int q = 0; q < 4; ++q) {
            float4 v = xp[q];
            m[4*q+0] = v.x; m[4*q+1] = v.y; m[4*q+2] = v.z; m[4*q+3] = v.w;
        }
        float a[16];
#pragma unroll
        for (int k = 0; k < 16; ++k) a[k] = 0.f;
        unsigned lo = offs[n], hi = offs[n + 1];
        const float4* ep = reinterpret_cast<const float4*>(e_new);
        for (unsigned j = lo; j < hi; ++j) {
            unsigned eid = elist[j];
            const float4* r = ep + (size_t)eid * 4;
#pragma unroll
            for (int q = 0; q < 4; ++q) {
                float4 v = r[q];
                a[4*q+0] += v.x; a[4*q+1] += v.y; a[4*q+2] += v.z; a[4*q+3] += v.w;
            }
        }
#pragma unroll
        for (int k = 0; k < 16; ++k) m[16 + k] = a[k];
    }

    float h[HID];
#pragma unroll
    for (int j = 0; j < HID; ++j) h[j] = b1[j];
#pragma unroll 4
    for (int i = 0; i < M2; ++i) {
        float mi = m[i];
        const float* wr = W1 + i * HID;
#pragma unroll
        for (int j = 0; j < HID; ++j) h[j] = fmaf(mi, wr[j], h[j]);
    }

    float o[ED];
#pragma unroll
    for (int k = 0; k < ED; ++k) o[k] = b2[k];
#pragma unroll 8
    for (int j = 0; j < HID; ++j) {
        float hj = fmaxf(h[j], 0.0f);
        const float* wr = W2 + j * ED;
#pragma unroll
        for (int k = 0; k < ED; ++k) o[k] = fmaf(hj, wr[k], o[k]);
    }

    float4* op = reinterpret_cast<float4*>(x_new) + n * 4;
    op[0] = make_float4(o[0], o[1], o[2],  o[3]);
    op[1] = make_float4(o[4], o[5], o[6],  o[7]);
    op[2] = make_float4(o[8], o[9], o[10], o[11]);
    op[3] = make_float4(o[12], o[13], o[14], o[15]);
}

// ---------------- legacy fallback kernels (ws too small): fp32 atomics + node MLP
__global__ __launch_bounds__(256) void edge_kernel_atomic(
    const float* __restrict__ x, const int* __restrict__ ei,
    const float* __restrict__ e,
    const float* __restrict__ W1, const float* __restrict__ b1,
    const float* __restrict__ W2, const float* __restrict__ b2,
    float* __restrict__ e_new, float* __restrict__ agg)
{
    int idx = blockIdx.x * blockDim.x + threadIdx.x;
    if (idx >= N_EDGES) return;
    int src = ei[idx];
    int dst = ei[N_EDGES + idx];
    float m[M1];
    const float4* xd = reinterpret_cast<const float4*>(x) + dst * 4;
    const float4* xs = reinterpret_cast<const float4*>(x) + src * 4;
    const float4* ep = reinterpret_cast<const float4*>(e) + (size_t)idx * 4;
#pragma unroll
    for (int q = 0; q < 4; ++q) { float4 v = xd[q]; m[4*q]=v.x; m[4*q+1]=v.y; m[4*q+2]=v.z; m[4*q+3]=v.w; }
#pragma unroll
    for (int q = 0; q < 4; ++q) { float4 v = xs[q]; m[16+4*q]=v.x; m[16+4*q+1]=v.y; m[16+4*q+2]=v.z; m[16+4*q+3]=v.w; }
#pragma unroll
    for (int q = 0; q < 4; ++q) { float4 v = ep[q]; m[32+4*q]=v.x; m[32+4*q+1]=v.y; m[32+4*q+2]=v.z; m[32+4*q+3]=v.w; }
    float h[HID];
#pragma unroll
    for (int j = 0; j < HID; ++j) h[j] = b1[j];
#pragma unroll 4
    for (int i = 0; i < M1; ++i) {
        float mi = m[i]; const float* wr = W1 + i * HID;
#pragma unroll
        for (int j = 0; j < HID; ++j) h[j] = fmaf(mi, wr[j], h[j]);
    }
    float o[ED];
#pragma unroll
    for (int k = 0; k < ED; ++k) o[k] = b2[k];
#pragma unroll 8
    for (int j = 0; j < HID; ++j) {
        float hj = fmaxf(h[j], 0.0f); const float* wr = W2 + j * ED;
#pragma unroll
        for (int k = 0; k < ED; ++k) o[k] = fmaf(hj, wr[k], o[k]);
    }
    float4* op = reinterpret_cast<float4*>(e_new) + (size_t)idx * 4;
    op[0] = make_float4(o[0],o[1],o[2],o[3]);
    op[1] = make_float4(o[4],o[5],o[6],o[7]);
    op[2] = make_float4(o[8],o[9],o[10],o[11]);
    op[3] = make_float4(o[12],o[13],o[14],o[15]);
    float* ag = agg + (size_t)dst * ED;
#pragma unroll
    for (int k = 0; k < ED; ++k) atomicAdd(ag + k, o[k]);
}

__global__ __launch_bounds__(256) void node_kernel(
    const float* __restrict__ x, const float* __restrict__ agg,
    const float* __restrict__ W1, const float* __restrict__ b1,
    const float* __restrict__ W2, const float* __restrict__ b2,
    float* __restrict__ x_new)
{
    int idx = blockIdx.x * blockDim.x + threadIdx.x;
    if (idx >= N_NODES) return;
    float m[M2];
    const float4* xp = reinterpret_cast<const float4*>(x) + idx * 4;
    const float4* ap = reinterpret_cast<const float4*>(agg) + idx * 4;
#pragma unroll
    for (int q = 0; q < 4; ++q) { float4 v = xp[q]; m[4*q]=v.x; m[4*q+1]=v.y; m[4*q+2]=v.z; m[4*q+3]=v.w; }
#pragma unroll
    for (int q = 0; q < 4; ++q) { float4 v = ap[q]; m[16+4*q]=v.x; m[16+4*q+1]=v.y; m[16+4*q+2]=v.z; m[16+4*q+3]=v.w; }
    float h[HID];
#pragma unroll
    for (int j = 0; j < HID; ++j) h[j] = b1[j];
#pragma unroll 4
    for (int i = 0; i < M2; ++i) {
        float mi = m[i]; const float* wr = W1 + i * HID;
#pragma unroll
        for (int j = 0; j < HID; ++j) h[j] = fmaf(mi, wr[j], h[j]);
    }
    float o[ED];
#pragma unroll
    for (int k = 0; k < ED; ++k) o[k] = b2[k];
#pragma unroll 8
    for (int j = 0; j < HID; ++j) {
        float hj = fmaxf(h[j], 0.0f); const float* wr = W2 + j * ED;
#pragma unroll
        for (int k = 0; k < ED; ++k) o[k] = fmaf(hj, wr[k], o[k]);
    }
    float4* op = reinterpret_cast<float4*>(x_new) + idx * 4;
    op[0] = make_float4(o[0],o[1],o[2],o[3]);
    op[1] = make_float4(o[4],o[5],o[6],o[7]);
    op[2] = make_float4(o[8],o[9],o[10],o[11]);
    op[3] = make_float4(o[12],o[13],o[14],o[15]);
}

static inline size_t align_up(size_t v, size_t a) { return (v + a - 1) / a * a; }

extern "C" void kernel_launch(void* const* d_in, const int* in_sizes, int n_in,
                              void* d_out, int out_size, void* d_ws, size_t ws_size,
                              hipStream_t stream) {
    const float* x     = (const float*)d_in[0];
    const int*   ei    = (const int*)  d_in[1];
    const float* e     = (const float*)d_in[2];
    const float* fR_W1 = (const float*)d_in[3];
    const float* fR_b1 = (const float*)d_in[4];
    const float* fR_W2 = (const float*)d_in[5];
    const float* fR_b2 = (const float*)d_in[6];
    const float* fO_W1 = (const float*)d_in[7];
    const float* fO_b1 = (const float*)d_in[8];
    const float* fO_W2 = (const float*)d_in[9];
    const float* fO_b2 = (const float*)d_in[10];

    float* x_new = (float*)d_out;                        // [N, 16]
    float* e_new = (float*)d_out + (size_t)N_NODES * ND; // [E, 16]

    char* ws = (char*)d_ws;
    size_t o = 0;
    unsigned*      offs  = (unsigned*)(ws + o);      o += align_up((size_t)(N_NODES + 1) * 4, 256);
    unsigned*      count = (unsigned*)(ws + o);      o += align_up((size_t)N_NODES * 4, 256);
    unsigned char* slot8 = (unsigned char*)(ws + o); o += align_up((size_t)N_EDGES, 256);
    unsigned*      pw    = (unsigned*)(ws + o);      o += align_up((size_t)NB * NWORDS * 4, 256);
    unsigned*      elist = (unsigned*)(ws + o);      o += align_up((size_t)N_EDGES * 4, 256);
    const size_t need = o;   // ~14.8 MB

    if (ws_size >= need) {
        // edge MLP (independent of CSR build)
        const int tiles_per_block = WAVES * TILES_PER_WAVE;  // 64
        const int nblocks = (N_TILES + tiles_per_block - 1) / tiles_per_block;
        edge_mfma_kernel<<<nblocks, 256, 0, stream>>>(
            x, ei, e, fR_W1, fR_b1, fR_W2, fR_b2, e_new);

        // CSR build: LDS histograms -> block prefixes -> node scan -> fill
        hist_kernel<<<NB, 1024, 0, stream>>>(ei, pw, slot8);
        bprefix_kernel<<<(NWORDS + 255) / 256, 256, 0, stream>>>(pw, count);
        scan_kernel<<<1, 1024, 0, stream>>>(count, offs);
        fill2_kernel<<<NB, 1024, 0, stream>>>(ei, offs, pw, slot8, elist);

        // fused gather-sum + node MLP
        agg_node_kernel<<<(N_NODES + 255) / 256, 256, 0, stream>>>(
            e_new, offs, elist, x, fO_W1, fO_b1, fO_W2, fO_b2, x_new);
    } else {
        float* agg0 = (float*)d_ws;
        hipMemsetAsync(agg0, 0, (size_t)N_NODES * ED * 4, stream);
        edge_kernel_atomic<<<N_EDGES / 256, 256, 0, stream>>>(
            x, ei, e, fR_W1, fR_b1, fR_W2, fR_b2, e_new, agg0);
        node_kernel<<<(N_NODES + 255) / 256, 256, 0, stream>>>(
            x, agg0, fO_W1, fO_b1, fO_W2, fO_b2, x_new);
    }
}

// Round 8
// 204.945 us; speedup vs baseline: 3.0120x; 1.3798x over previous
//
#include <hip/hip_runtime.h>
#include <hip/hip_bf16.h>

#define N_NODES 50000
#define N_EDGES 1600000
#define ND 16
#define ED 16
#define HID 64
#define M1 (2*ND+ED)   // 48
#define M2 (ND+ED)     // 32
#define N_TILES (N_EDGES / 16)   // 100000
#define WAVES 4
#define TILES_PER_WAVE 16

// CSR-build geometry
#define NB 128
#define CHUNK (N_EDGES / NB)     // 12500
#define NWORDS (N_NODES / 4)     // 12500 packed-u8 histogram words

// scan geometry
#define SCAN_BS 256
#define SCAN_NB ((N_NODES + SCAN_BS - 1) / SCAN_BS)   // 196

typedef short bf16x8 __attribute__((ext_vector_type(8)));
typedef float f32x4  __attribute__((ext_vector_type(4)));

__device__ inline unsigned pack_bf16(float a, float b) {
    __hip_bfloat162 p = __float22bfloat162_rn(float2{a, b});
    return *reinterpret_cast<unsigned*>(&p);
}

// ---------------- hist: per-block LDS histogram (u8 x4 packed) + local slot
__global__ __launch_bounds__(1024) void hist_kernel(
    const int* __restrict__ ei,
    unsigned* __restrict__ partial_w,    // [NB][NWORDS]
    unsigned char* __restrict__ slot8)   // [E]
{
    __shared__ unsigned hist[NWORDS];
    const int b = blockIdx.x, t = threadIdx.x;
    for (int w = t; w < NWORDS; w += 1024) hist[w] = 0u;
    __syncthreads();
    const int base = b * CHUNK;
    for (int i = t; i < CHUNK; i += 1024) {
        int idx = base + i;
        int dst = ei[N_EDGES + idx];
        unsigned sh = (unsigned)(dst & 3) * 8u;
        unsigned old = atomicAdd(&hist[dst >> 2], 1u << sh);
        slot8[idx] = (unsigned char)((old >> sh) & 0xffu);
    }
    __syncthreads();
    unsigned* out = partial_w + (size_t)b * NWORDS;
    for (int w = t; w < NWORDS; w += 1024) out[w] = hist[w];
}

// ---------------- bprefix: in-place exclusive prefix over blocks per node
__global__ __launch_bounds__(256) void bprefix_kernel(
    unsigned* __restrict__ partial_w, unsigned* __restrict__ count)
{
    int w = blockIdx.x * blockDim.x + threadIdx.x;
    if (w >= NWORDS) return;
    unsigned r0 = 0, r1 = 0, r2 = 0, r3 = 0;
#pragma unroll 8
    for (int b = 0; b < NB; ++b) {
        size_t o = (size_t)b * NWORDS + w;
        unsigned v = partial_w[o];
        partial_w[o] = (r0 & 0xff) | ((r1 & 0xff) << 8) |
                       ((r2 & 0xff) << 16) | ((r3 & 0xff) << 24);
        r0 += v & 0xffu; r1 += (v >> 8) & 0xffu;
        r2 += (v >> 16) & 0xffu; r3 += (v >> 24) & 0xffu;
    }
    count[w * 4 + 0] = r0; count[w * 4 + 1] = r1;
    count[w * 4 + 2] = r2; count[w * 4 + 3] = r3;
}

// ---------------- 3-phase parallel scan: count[N] -> offs[N+1]
__global__ __launch_bounds__(SCAN_BS) void scan_blocks_kernel(
    const unsigned* __restrict__ count, unsigned* __restrict__ offs,
    unsigned* __restrict__ bsum)
{
    __shared__ unsigned s[SCAN_BS];
    const int b = blockIdx.x, t = threadIdx.x;
    const int n = b * SCAN_BS + t;
    unsigned v = (n < N_NODES) ? count[n] : 0u;
    s[t] = v;
    __syncthreads();
    for (int d = 1; d < SCAN_BS; d <<= 1) {
        unsigned u = (t >= d) ? s[t - d] : 0u;
        __syncthreads();
        s[t] += u;
        __syncthreads();
    }
    if (n < N_NODES) offs[n] = s[t] - v;           // exclusive
    if (t == SCAN_BS - 1) bsum[b] = s[t];
}

__global__ __launch_bounds__(256) void scan_bsum_kernel(
    const unsigned* __restrict__ bsum, unsigned* __restrict__ bbase,
    unsigned* __restrict__ offs)
{
    __shared__ unsigned s[256];
    const int t = threadIdx.x;
    unsigned v = (t < SCAN_NB) ? bsum[t] : 0u;
    s[t] = v;
    __syncthreads();
    for (int d = 1; d < 256; d <<= 1) {
        unsigned u = (t >= d) ? s[t - d] : 0u;
        __syncthreads();
        s[t] += u;
        __syncthreads();
    }
    if (t < SCAN_NB) bbase[t] = s[t] - v;
    if (t == SCAN_NB - 1) offs[N_NODES] = s[t];
}

__global__ __launch_bounds__(SCAN_BS) void scan_add_kernel(
    unsigned* __restrict__ offs, const unsigned* __restrict__ bbase)
{
    const int n = blockIdx.x * SCAN_BS + threadIdx.x;
    if (n < N_NODES) offs[n] += bbase[blockIdx.x];
}

// ---------------- fill2: elist[offs[dst] + bp[b][dst] + slot8[idx]] = idx
__global__ __launch_bounds__(1024) void fill2_kernel(
    const int* __restrict__ ei, const unsigned* __restrict__ offs,
    const unsigned* __restrict__ bp_w,
    const unsigned char* __restrict__ slot8,
    unsigned* __restrict__ elist)
{
    const int b = blockIdx.x, t = threadIdx.x;
    const int base = b * CHUNK;
    const unsigned* bpb = bp_w + (size_t)b * NWORDS;
    for (int i = t; i < CHUNK; i += 1024) {
        int idx = base + i;
        int dst = ei[N_EDGES + idx];
        unsigned pre = (bpb[dst >> 2] >> ((unsigned)(dst & 3) * 8u)) & 0xffu;
        unsigned pos = offs[dst] + pre + (unsigned)slot8[idx];
        elist[pos] = (unsigned)idx;
    }
}

// ---------------- MFMA edge kernel, software-pipelined (2-tile rotation)
__global__ __launch_bounds__(256) void edge_mfma_kernel(
    const float* __restrict__ x, const int* __restrict__ ei,
    const float* __restrict__ e,
    const float* __restrict__ W1, const float* __restrict__ b1,
    const float* __restrict__ W2, const float* __restrict__ b2,
    float* __restrict__ e_new)
{
    __shared__ __align__(16) char lds[WAVES * (2048 + 4096)];
    const int lane  = threadIdx.x & 63;
    const int wave  = threadIdx.x >> 6;
    char* mbase = lds + wave * 2048;
    char* hbase = lds + WAVES * 2048 + wave * 4096;

    const int row16 = lane & 15;
    const int kg    = lane >> 4;

    // ---- weight fragments in registers ----
    bf16x8 w1f[4][2];
#pragma unroll
    for (int t = 0; t < 4; ++t)
#pragma unroll
        for (int s = 0; s < 2; ++s) {
            union { bf16x8 v; unsigned u[4]; } fr;
#pragma unroll
            for (int r = 0; r < 4; ++r) {
                int k0 = s * 32 + kg * 8 + 2 * r;
                int n  = t * 16 + row16;
                float a = (k0     < M1) ? W1[k0 * HID + n]       : 0.f;
                float b = (k0 + 1 < M1) ? W1[(k0 + 1) * HID + n] : 0.f;
                fr.u[r] = pack_bf16(a, b);
            }
            w1f[t][s] = fr.v;
        }
    bf16x8 w2f[2];
#pragma unroll
    for (int s = 0; s < 2; ++s) {
        union { bf16x8 v; unsigned u[4]; } fr;
#pragma unroll
        for (int r = 0; r < 4; ++r) {
            int k0 = s * 32 + kg * 8 + 2 * r;
            fr.u[r] = pack_bf16(W2[k0 * ED + row16], W2[(k0 + 1) * ED + row16]);
        }
        w2f[s] = fr.v;
    }
    float b1v[4];
#pragma unroll
    for (int t = 0; t < 4; ++t) b1v[t] = b1[t * 16 + row16];
    const float b2v = b2[row16];

    const int erow = lane >> 2;
    const int q    = lane & 3;
    const unsigned swz = ((unsigned)erow & 7) << 4;
    const unsigned asw = ((unsigned)row16 & 7) << 4;

    // zero the K-pad (bf16 cols 48..63) once
    {
        unsigned off = ((unsigned)erow * 128 + 96 + q * 8) ^ swz;
        *(unsigned long long*)(mbase + off) = 0ull;
    }

    const int wtile0 = ((int)blockIdx.x * WAVES + wave) * TILES_PER_WAVE;
    if (wtile0 >= N_TILES) return;

    const float4* x4 = reinterpret_cast<const float4*>(x);
    const float4* e4 = reinterpret_cast<const float4*>(e);

    auto eidx_of = [&](int tl) {
        int tc = tl < N_TILES - 1 ? tl : N_TILES - 1;
        return tc * 16 + erow;
    };

    auto stage = [&](const float4& vd, const float4& vs, const float4& ve) {
        {
            unsigned off = ((unsigned)erow * 128 + 0 + q * 8) ^ swz;
            unsigned lo = pack_bf16(vd.x, vd.y), hi = pack_bf16(vd.z, vd.w);
            *(unsigned long long*)(mbase + off) = ((unsigned long long)hi << 32) | lo;
        }
        {
            unsigned off = ((unsigned)erow * 128 + 32 + q * 8) ^ swz;
            unsigned lo = pack_bf16(vs.x, vs.y), hi = pack_bf16(vs.z, vs.w);
            *(unsigned long long*)(mbase + off) = ((unsigned long long)hi << 32) | lo;
        }
        {
            unsigned off = ((unsigned)erow * 128 + 64 + q * 8) ^ swz;
            unsigned lo = pack_bf16(ve.x, ve.y), hi = pack_bf16(ve.z, ve.w);
            *(unsigned long long*)(mbase + off) = ((unsigned long long)hi << 32) | lo;
        }
    };

    auto compute_store = [&](int tile) {
        bf16x8 a0 = *(bf16x8*)(mbase + (((unsigned)row16 * 128 +  0 + kg * 16) ^ asw));
        bf16x8 a1 = *(bf16x8*)(mbase + (((unsigned)row16 * 128 + 64 + kg * 16) ^ asw));

        f32x4 acc[4];
#pragma unroll
        for (int tt = 0; tt < 4; ++tt) {
            acc[tt] = (f32x4){0.f, 0.f, 0.f, 0.f};
            acc[tt] = __builtin_amdgcn_mfma_f32_16x16x32_bf16(a0, w1f[tt][0], acc[tt], 0, 0, 0);
            acc[tt] = __builtin_amdgcn_mfma_f32_16x16x32_bf16(a1, w1f[tt][1], acc[tt], 0, 0, 0);
        }

#pragma unroll
        for (int tt = 0; tt < 4; ++tt) {
#pragma unroll
            for (int r = 0; r < 4; ++r) {
                float hv = fmaxf(acc[tt][r] + b1v[tt], 0.f);
                unsigned hrow = (unsigned)(kg * 4 + r);
                unsigned off = (hrow * 256 + (unsigned)(tt * 16 + row16) * 4) ^ ((hrow & 7) << 4);
                *(float*)(hbase + off) = hv;
            }
        }

        bf16x8 a2[2];
#pragma unroll
        for (int s = 0; s < 2; ++s) {
            unsigned base = (unsigned)row16 * 256 + s * 128 + kg * 32;
            f32x4 lo = *(f32x4*)(hbase + ((base +  0) ^ asw));
            f32x4 hi = *(f32x4*)(hbase + ((base + 16) ^ asw));
            union { bf16x8 v; unsigned u[4]; } fr;
            fr.u[0] = pack_bf16(lo[0], lo[1]);
            fr.u[1] = pack_bf16(lo[2], lo[3]);
            fr.u[2] = pack_bf16(hi[0], hi[1]);
            fr.u[3] = pack_bf16(hi[2], hi[3]);
            a2[s] = fr.v;
        }

        f32x4 oacc = (f32x4){0.f, 0.f, 0.f, 0.f};
        oacc = __builtin_amdgcn_mfma_f32_16x16x32_bf16(a2[0], w2f[0], oacc, 0, 0, 0);
        oacc = __builtin_amdgcn_mfma_f32_16x16x32_bf16(a2[1], w2f[1], oacc, 0, 0, 0);

        if (tile < N_TILES) {
            int ebase = tile * 16;
#pragma unroll
            for (int r = 0; r < 4; ++r) {
                e_new[(size_t)(ebase + kg * 4 + r) * 16 + row16] = oacc[r] + b2v;
            }
        }
    };

    // ---- pipeline prologue ----
    int eA = eidx_of(wtile0 + 0);
    int srcA = ei[eA], dstA = ei[N_EDGES + eA];
    int eB = eidx_of(wtile0 + 1);
    int srcB = ei[eB], dstB = ei[N_EDGES + eB];
    float4 vdA = x4[dstA * 4 + q];
    float4 vsA = x4[srcA * 4 + q];
    float4 veA = e4[(size_t)eA * 4 + q];

    for (int i = 0; i < TILES_PER_WAVE / 2; ++i) {
        const int tA = wtile0 + 2 * i;
        const int tB = tA + 1;

        // ---- tile A ----
        stage(vdA, vsA, veA);
        // issue gathers for tile B (ei for B loaded 1 iteration ago)
        float4 vdB = x4[dstB * 4 + q];
        float4 vsB = x4[srcB * 4 + q];
        float4 veB = e4[(size_t)eB * 4 + q];
        // issue ei for tile A+2
        eA = eidx_of(tA + 2);
        srcA = ei[eA]; dstA = ei[N_EDGES + eA];
        compute_store(tA);

        // ---- tile B ----
        stage(vdB, vsB, veB);
        // issue gathers for tile A+2 (ei just landed during compute of A)
        vdA = x4[dstA * 4 + q];
        vsA = x4[srcA * 4 + q];
        veA = e4[(size_t)eA * 4 + q];
        // issue ei for tile B+2
        eB = eidx_of(tB + 2);
        srcB = ei[eB]; dstB = ei[N_EDGES + eB];
        compute_store(tB);
    }
}

// ---------------- fused agg + node MLP: 1 thread per node
__global__ __launch_bounds__(256) void agg_node_kernel(
    const float* __restrict__ e_new, const unsigned* __restrict__ offs,
    const unsigned* __restrict__ elist, const float* __restrict__ x,
    const float* __restrict__ W1, const float* __restrict__ b1,
    const float* __restrict__ W2, const float* __restrict__ b2,
    float* __restrict__ x_new)
{
    int n = blockIdx.x * blockDim.x + threadIdx.x;
    if (n >= N_NODES) return;

    float m[M2];
    {
        const float4* xp = reinterpret_cast<const float4*>(x) + n * 4;
#pragma unroll
        for (int q = 0; q < 4; ++q) {
            float4 v = xp[q];
            m[4*q+0] = v.x; m[4*q+1] = v.y; m[4*q+2] = v.z; m[4*q+3] = v.w;
        }
        float a[16];
#pragma unroll
        for (int k = 0; k < 16; ++k) a[k] = 0.f;
        unsigned lo = offs[n], hi = offs[n + 1];
        const float4* ep = reinterpret_cast<const float4*>(e_new);
        for (unsigned j = lo; j < hi; ++j) {
            unsigned eid = elist[j];
            const float4* r = ep + (size_t)eid * 4;
#pragma unroll
            for (int q = 0; q < 4; ++q) {
                float4 v = r[q];
                a[4*q+0] += v.x; a[4*q+1] += v.y; a[4*q+2] += v.z; a[4*q+3] += v.w;
            }
        }
#pragma unroll
        for (int k = 0; k < 16; ++k) m[16 + k] = a[k];
    }

    float h[HID];
#pragma unroll
    for (int j = 0; j < HID; ++j) h[j] = b1[j];
#pragma unroll 4
    for (int i = 0; i < M2; ++i) {
        float mi = m[i];
        const float* wr = W1 + i * HID;
#pragma unroll
        for (int j = 0; j < HID; ++j) h[j] = fmaf(mi, wr[j], h[j]);
    }

    float o[ED];
#pragma unroll
    for (int k = 0; k < ED; ++k) o[k] = b2[k];
#pragma unroll 8
    for (int j = 0; j < HID; ++j) {
        float hj = fmaxf(h[j], 0.0f);
        const float* wr = W2 + j * ED;
#pragma unroll
        for (int k = 0; k < ED; ++k) o[k] = fmaf(hj, wr[k], o[k]);
    }

    float4* op = reinterpret_cast<float4*>(x_new) + n * 4;
    op[0] = make_float4(o[0], o[1], o[2],  o[3]);
    op[1] = make_float4(o[4], o[5], o[6],  o[7]);
    op[2] = make_float4(o[8], o[9], o[10], o[11]);
    op[3] = make_float4(o[12], o[13], o[14], o[15]);
}

// ---------------- legacy fallback kernels (ws too small)
__global__ __launch_bounds__(256) void edge_kernel_atomic(
    const float* __restrict__ x, const int* __restrict__ ei,
    const float* __restrict__ e,
    const float* __restrict__ W1, const float* __restrict__ b1,
    const float* __restrict__ W2, const float* __restrict__ b2,
    float* __restrict__ e_new, float* __restrict__ agg)
{
    int idx = blockIdx.x * blockDim.x + threadIdx.x;
    if (idx >= N_EDGES) return;
    int src = ei[idx];
    int dst = ei[N_EDGES + idx];
    float m[M1];
    const float4* xd = reinterpret_cast<const float4*>(x) + dst * 4;
    const float4* xs = reinterpret_cast<const float4*>(x) + src * 4;
    const float4* ep = reinterpret_cast<const float4*>(e) + (size_t)idx * 4;
#pragma unroll
    for (int q = 0; q < 4; ++q) { float4 v = xd[q]; m[4*q]=v.x; m[4*q+1]=v.y; m[4*q+2]=v.z; m[4*q+3]=v.w; }
#pragma unroll
    for (int q = 0; q < 4; ++q) { float4 v = xs[q]; m[16+4*q]=v.x; m[16+4*q+1]=v.y; m[16+4*q+2]=v.z; m[16+4*q+3]=v.w; }
#pragma unroll
    for (int q = 0; q < 4; ++q) { float4 v = ep[q]; m[32+4*q]=v.x; m[32+4*q+1]=v.y; m[32+4*q+2]=v.z; m[32+4*q+3]=v.w; }
    float h[HID];
#pragma unroll
    for (int j = 0; j < HID; ++j) h[j] = b1[j];
#pragma unroll 4
    for (int i = 0; i < M1; ++i) {
        float mi = m[i]; const float* wr = W1 + i * HID;
#pragma unroll
        for (int j = 0; j < HID; ++j) h[j] = fmaf(mi, wr[j], h[j]);
    }
    float o[ED];
#pragma unroll
    for (int k = 0; k < ED; ++k) o[k] = b2[k];
#pragma unroll 8
    for (int j = 0; j < HID; ++j) {
        float hj = fmaxf(h[j], 0.0f); const float* wr = W2 + j * ED;
#pragma unroll
        for (int k = 0; k < ED; ++k) o[k] = fmaf(hj, wr[k], o[k]);
    }
    float4* op = reinterpret_cast<float4*>(e_new) + (size_t)idx * 4;
    op[0] = make_float4(o[0],o[1],o[2],o[3]);
    op[1] = make_float4(o[4],o[5],o[6],o[7]);
    op[2] = make_float4(o[8],o[9],o[10],o[11]);
    op[3] = make_float4(o[12],o[13],o[14],o[15]);
    float* ag = agg + (size_t)dst * ED;
#pragma unroll
    for (int k = 0; k < ED; ++k) atomicAdd(ag + k, o[k]);
}

__global__ __launch_bounds__(256) void node_kernel(
    const float* __restrict__ x, const float* __restrict__ agg,
    const float* __restrict__ W1, const float* __restrict__ b1,
    const float* __restrict__ W2, const float* __restrict__ b2,
    float* __restrict__ x_new)
{
    int idx = blockIdx.x * blockDim.x + threadIdx.x;
    if (idx >= N_NODES) return;
    float m[M2];
    const float4* xp = reinterpret_cast<const float4*>(x) + idx * 4;
    const float4* ap = reinterpret_cast<const float4*>(agg) + idx * 4;
#pragma unroll
    for (int q = 0; q < 4; ++q) { float4 v = xp[q]; m[4*q]=v.x; m[4*q+1]=v.y; m[4*q+2]=v.z; m[4*q+3]=v.w; }
#pragma unroll
    for (int q = 0; q < 4; ++q) { float4 v = ap[q]; m[16+4*q]=v.x; m[16+4*q+1]=v.y; m[16+4*q+2]=v.z; m[16+4*q+3]=v.w; }
    float h[HID];
#pragma unroll
    for (int j = 0; j < HID; ++j) h[j] = b1[j];
#pragma unroll 4
    for (int i = 0; i < M2; ++i) {
        float mi = m[i]; const float* wr = W1 + i * HID;
#pragma unroll
        for (int j = 0; j < HID; ++j) h[j] = fmaf(mi, wr[j], h[j]);
    }
    float o[ED];
#pragma unroll
    for (int k = 0; k < ED; ++k) o[k] = b2[k];
#pragma unroll 8
    for (int j = 0; j < HID; ++j) {
        float hj = fmaxf(h[j], 0.0f); const float* wr = W2 + j * ED;
#pragma unroll
        for (int k = 0; k < ED; ++k) o[k] = fmaf(hj, wr[k], o[k]);
    }
    float4* op = reinterpret_cast<float4*>(x_new) + idx * 4;
    op[0] = make_float4(o[0],o[1],o[2],o[3]);
    op[1] = make_float4(o[4],o[5],o[6],o[7]);
    op[2] = make_float4(o[8],o[9],o[10],o[11]);
    op[3] = make_float4(o[12],o[13],o[14],o[15]);
}

static inline size_t align_up(size_t v, size_t a) { return (v + a - 1) / a * a; }

extern "C" void kernel_launch(void* const* d_in, const int* in_sizes, int n_in,
                              void* d_out, int out_size, void* d_ws, size_t ws_size,
                              hipStream_t stream) {
    const float* x     = (const float*)d_in[0];
    const int*   ei    = (const int*)  d_in[1];
    const float* e     = (const float*)d_in[2];
    const float* fR_W1 = (const float*)d_in[3];
    const float* fR_b1 = (const float*)d_in[4];
    const float* fR_W2 = (const float*)d_in[5];
    const float* fR_b2 = (const float*)d_in[6];
    const float* fO_W1 = (const float*)d_in[7];
    const float* fO_b1 = (const float*)d_in[8];
    const float* fO_W2 = (const float*)d_in[9];
    const float* fO_b2 = (const float*)d_in[10];

    float* x_new = (float*)d_out;                        // [N, 16]
    float* e_new = (float*)d_out + (size_t)N_NODES * ND; // [E, 16]

    char* ws = (char*)d_ws;
    size_t o = 0;
    unsigned*      offs  = (unsigned*)(ws + o);      o += align_up((size_t)(N_NODES + 1) * 4, 256);
    unsigned*      count = (unsigned*)(ws + o);      o += align_up((size_t)N_NODES * 4, 256);
    unsigned char* slot8 = (unsigned char*)(ws + o); o += align_up((size_t)N_EDGES, 256);
    unsigned*      pw    = (unsigned*)(ws + o);      o += align_up((size_t)NB * NWORDS * 4, 256);
    unsigned*      elist = (unsigned*)(ws + o);      o += align_up((size_t)N_EDGES * 4, 256);
    unsigned*      bsum  = (unsigned*)(ws + o);      o += align_up((size_t)SCAN_NB * 4, 256);
    unsigned*      bbase = (unsigned*)(ws + o);      o += align_up((size_t)SCAN_NB * 4, 256);
    const size_t need = o;   // ~14.8 MB

    if (ws_size >= need) {
        const int tiles_per_block = WAVES * TILES_PER_WAVE;  // 64
        const int nblocks = (N_TILES + tiles_per_block - 1) / tiles_per_block;
        edge_mfma_kernel<<<nblocks, 256, 0, stream>>>(
            x, ei, e, fR_W1, fR_b1, fR_W2, fR_b2, e_new);

        hist_kernel<<<NB, 1024, 0, stream>>>(ei, pw, slot8);
        bprefix_kernel<<<(NWORDS + 255) / 256, 256, 0, stream>>>(pw, count);
        scan_blocks_kernel<<<SCAN_NB, SCAN_BS, 0, stream>>>(count, offs, bsum);
        scan_bsum_kernel<<<1, 256, 0, stream>>>(bsum, bbase, offs);
        scan_add_kernel<<<SCAN_NB, SCAN_BS, 0, stream>>>(offs, bbase);
        fill2_kernel<<<NB, 1024, 0, stream>>>(ei, offs, pw, slot8, elist);

        agg_node_kernel<<<(N_NODES + 255) / 256, 256, 0, stream>>>(
            e_new, offs, elist, x, fO_W1, fO_b1, fO_W2, fO_b2, x_new);
    } else {
        float* agg0 = (float*)d_ws;
        hipMemsetAsync(agg0, 0, (size_t)N_NODES * ED * 4, stream);
        edge_kernel_atomic<<<N_EDGES / 256, 256, 0, stream>>>(
            x, ei, e, fR_W1, fR_b1, fR_W2, fR_b2, e_new, agg0);
        node_kernel<<<(N_NODES + 255) / 256, 256, 0, stream>>>(
            x, agg0, fO_W1, fO_b1, fO_W2, fO_b2, x_new);
    }
}

// Round 9
// 198.651 us; speedup vs baseline: 3.1075x; 1.0317x over previous
//
#include <hip/hip_runtime.h>
#include <hip/hip_bf16.h>

#define N_NODES 50000
#define N_EDGES 1600000
#define ND 16
#define ED 16
#define HID 64
#define M1 (2*ND+ED)   // 48
#define M2 (ND+ED)     // 32
#define N_TILES (N_EDGES / 16)   // 100000
#define WAVES 4
#define TILES_PER_WAVE 16

// CSR-build geometry
#define NB 128
#define CHUNK (N_EDGES / NB)     // 12500
#define NWORDS (N_NODES / 4)     // 12500

// scan geometry
#define SCAN_BS 256
#define SCAN_NB ((N_NODES + SCAN_BS - 1) / SCAN_BS)   // 196

// transpose scratch: 32 rows x 20 words (stride 20 => 2-way banks max), x2 parity
#define TROW 20
#define TBUF (32 * TROW)         // 640 words = 2560 B per buffer

// node-MLP geometry
#define NT_NODE (N_NODES / 16)   // 3125 exactly
#define TPW_N 4                  // tiles per wave; 16/block -> 196 blocks

typedef short bf16x8 __attribute__((ext_vector_type(8)));
typedef float f32x4  __attribute__((ext_vector_type(4)));

__device__ inline unsigned pack_bf16(float a, float b) {
    __hip_bfloat162 p = __float22bfloat162_rn(float2{a, b});
    return *reinterpret_cast<unsigned*>(&p);
}

// ---------------- hist: per-block LDS histogram (u8 x4 packed) + local slot
__global__ __launch_bounds__(1024) void hist_kernel(
    const int* __restrict__ ei,
    unsigned* __restrict__ partial_w,    // [NB][NWORDS]
    unsigned char* __restrict__ slot8)   // [E]
{
    __shared__ unsigned hist[NWORDS];
    const int b = blockIdx.x, t = threadIdx.x;
    for (int w = t; w < NWORDS; w += 1024) hist[w] = 0u;
    __syncthreads();
    const int base = b * CHUNK;
    for (int i = t; i < CHUNK; i += 1024) {
        int idx = base + i;
        int dst = ei[N_EDGES + idx];
        unsigned sh = (unsigned)(dst & 3) * 8u;
        unsigned old = atomicAdd(&hist[dst >> 2], 1u << sh);
        slot8[idx] = (unsigned char)((old >> sh) & 0xffu);
    }
    __syncthreads();
    unsigned* out = partial_w + (size_t)b * NWORDS;
    for (int w = t; w < NWORDS; w += 1024) out[w] = hist[w];
}

// ---------------- bprefix: in-place exclusive prefix over blocks per node
__global__ __launch_bounds__(256) void bprefix_kernel(
    unsigned* __restrict__ partial_w, unsigned* __restrict__ count)
{
    int w = blockIdx.x * blockDim.x + threadIdx.x;
    if (w >= NWORDS) return;
    unsigned r0 = 0, r1 = 0, r2 = 0, r3 = 0;
#pragma unroll 8
    for (int b = 0; b < NB; ++b) {
        size_t o = (size_t)b * NWORDS + w;
        unsigned v = partial_w[o];
        partial_w[o] = (r0 & 0xff) | ((r1 & 0xff) << 8) |
                       ((r2 & 0xff) << 16) | ((r3 & 0xff) << 24);
        r0 += v & 0xffu; r1 += (v >> 8) & 0xffu;
        r2 += (v >> 16) & 0xffu; r3 += (v >> 24) & 0xffu;
    }
    count[w * 4 + 0] = r0; count[w * 4 + 1] = r1;
    count[w * 4 + 2] = r2; count[w * 4 + 3] = r3;
}

// ---------------- 3-phase parallel scan: count[N] -> offs[N+1]
__global__ __launch_bounds__(SCAN_BS) void scan_blocks_kernel(
    const unsigned* __restrict__ count, unsigned* __restrict__ offs,
    unsigned* __restrict__ bsum)
{
    __shared__ unsigned s[SCAN_BS];
    const int b = blockIdx.x, t = threadIdx.x;
    const int n = b * SCAN_BS + t;
    unsigned v = (n < N_NODES) ? count[n] : 0u;
    s[t] = v;
    __syncthreads();
    for (int d = 1; d < SCAN_BS; d <<= 1) {
        unsigned u = (t >= d) ? s[t - d] : 0u;
        __syncthreads();
        s[t] += u;
        __syncthreads();
    }
    if (n < N_NODES) offs[n] = s[t] - v;
    if (t == SCAN_BS - 1) bsum[b] = s[t];
}

__global__ __launch_bounds__(256) void scan_bsum_kernel(
    const unsigned* __restrict__ bsum, unsigned* __restrict__ bbase,
    unsigned* __restrict__ offs)
{
    __shared__ unsigned s[256];
    const int t = threadIdx.x;
    unsigned v = (t < SCAN_NB) ? bsum[t] : 0u;
    s[t] = v;
    __syncthreads();
    for (int d = 1; d < 256; d <<= 1) {
        unsigned u = (t >= d) ? s[t - d] : 0u;
        __syncthreads();
        s[t] += u;
        __syncthreads();
    }
    if (t < SCAN_NB) bbase[t] = s[t] - v;
    if (t == SCAN_NB - 1) offs[N_NODES] = s[t];
}

__global__ __launch_bounds__(SCAN_BS) void scan_add_kernel(
    unsigned* __restrict__ offs, const unsigned* __restrict__ bbase)
{
    const int n = blockIdx.x * SCAN_BS + threadIdx.x;
    if (n < N_NODES) offs[n] += bbase[blockIdx.x];
}

// ---------------- fill2: elist[offs[dst] + bp[b][dst] + slot8[idx]] = idx
__global__ __launch_bounds__(1024) void fill2_kernel(
    const int* __restrict__ ei, const unsigned* __restrict__ offs,
    const unsigned* __restrict__ bp_w,
    const unsigned char* __restrict__ slot8,
    unsigned* __restrict__ elist)
{
    const int b = blockIdx.x, t = threadIdx.x;
    const int base = b * CHUNK;
    const unsigned* bpb = bp_w + (size_t)b * NWORDS;
    for (int i = t; i < CHUNK; i += 1024) {
        int idx = base + i;
        int dst = ei[N_EDGES + idx];
        unsigned pre = (bpb[dst >> 2] >> ((unsigned)(dst & 3) * 8u)) & 0xffu;
        unsigned pos = offs[dst] + pre + (unsigned)slot8[idx];
        elist[pos] = (unsigned)idx;
    }
}

// ---------------- MFMA edge kernel: swapped operands, LDS-free layer 1
// h^T = W1^T . m^T  (A=W1-frags, B=m-frags loaded straight from global)
// layer-2 transpose through tiny stride-20 LDS; coalesced float4 C-store.
__global__ __launch_bounds__(256) void edge_mfma_kernel(
    const float* __restrict__ x, const int* __restrict__ ei,
    const float* __restrict__ e,
    const float* __restrict__ W1, const float* __restrict__ b1,
    const float* __restrict__ W2, const float* __restrict__ b2,
    float* __restrict__ e_new)
{
    __shared__ unsigned Tld[WAVES * 2 * TBUF];   // 20 KB
    const int lane = threadIdx.x & 63;
    const int wave = threadIdx.x >> 6;
    unsigned* T0 = Tld + wave * 2 * TBUF;
    unsigned* T1 = T0 + TBUF;
    const int edge = lane & 15;
    const int kg   = lane >> 4;
    const bool lo32 = (kg < 2);
    const int h8 = kg & 1;

    // ---- weight fragments (same packing as verified rounds 6-8) ----
    bf16x8 w1f[4][2];
#pragma unroll
    for (int t = 0; t < 4; ++t)
#pragma unroll
        for (int s = 0; s < 2; ++s) {
            union { bf16x8 v; unsigned u[4]; } fr;
#pragma unroll
            for (int r = 0; r < 4; ++r) {
                int k0 = s * 32 + kg * 8 + 2 * r;
                int n  = t * 16 + edge;
                float a = (k0     < M1) ? W1[k0 * HID + n]       : 0.f;
                float b = (k0 + 1 < M1) ? W1[(k0 + 1) * HID + n] : 0.f;
                fr.u[r] = pack_bf16(a, b);
            }
            w1f[t][s] = fr.v;
        }
    bf16x8 w2f[2];
#pragma unroll
    for (int s = 0; s < 2; ++s) {
        union { bf16x8 v; unsigned u[4]; } fr;
#pragma unroll
        for (int r = 0; r < 4; ++r) {
            int k0 = s * 32 + kg * 8 + 2 * r;
            fr.u[r] = pack_bf16(W2[k0 * ED + edge], W2[(k0 + 1) * ED + edge]);
        }
        w2f[s] = fr.v;
    }
    float b1v[4][4];
#pragma unroll
    for (int t = 0; t < 4; ++t)
#pragma unroll
        for (int r = 0; r < 4; ++r) b1v[t][r] = b1[t * 16 + kg * 4 + r];
    float b2v[4];
#pragma unroll
    for (int r = 0; r < 4; ++r) b2v[r] = b2[kg * 4 + r];

    const int wtile0 = ((int)blockIdx.x * WAVES + wave) * TILES_PER_WAVE;
    if (wtile0 >= N_TILES) return;

    const float4* x4 = reinterpret_cast<const float4*>(x);
    const float4* e4 = reinterpret_cast<const float4*>(e);

    auto nid_of = [&](int tl) -> int {
        int tc = tl < N_TILES ? tl : N_TILES - 1;
        return ei[(lo32 ? N_EDGES : 0) + tc * 16 + edge];  // lo: dst, hi: src
    };
    auto load_x = [&](int nid, float4& a, float4& b) {
        size_t o = (size_t)nid * 4 + h8 * 2;
        a = x4[o]; b = x4[o + 1];
    };
    auto load_e = [&](int tl, float4& a, float4& b) {
        if (lo32) {
            int tc = tl < N_TILES ? tl : N_TILES - 1;
            size_t o = (size_t)(tc * 16 + edge) * 4 + kg * 2;
            a = e4[o]; b = e4[o + 1];
        } else {
            a = make_float4(0.f, 0.f, 0.f, 0.f);
            b = make_float4(0.f, 0.f, 0.f, 0.f);
        }
    };

    auto compute = [&](int tile, unsigned* T,
                       const float4& g0, const float4& g1,
                       const float4& ge0, const float4& ge1) {
        union { bf16x8 v; unsigned u[4]; } fa, fb;
        fa.u[0] = pack_bf16(g0.x, g0.y);  fa.u[1] = pack_bf16(g0.z, g0.w);
        fa.u[2] = pack_bf16(g1.x, g1.y);  fa.u[3] = pack_bf16(g1.z, g1.w);
        fb.u[0] = pack_bf16(ge0.x, ge0.y); fb.u[1] = pack_bf16(ge0.z, ge0.w);
        fb.u[2] = pack_bf16(ge1.x, ge1.y); fb.u[3] = pack_bf16(ge1.z, ge1.w);

        const f32x4 z = {0.f, 0.f, 0.f, 0.f};
        f32x4 acc[4];
#pragma unroll
        for (int tt = 0; tt < 4; ++tt) {
            acc[tt] = __builtin_amdgcn_mfma_f32_16x16x32_bf16(w1f[tt][0], fa.v, z, 0, 0, 0);
            acc[tt] = __builtin_amdgcn_mfma_f32_16x16x32_bf16(w1f[tt][1], fb.v, acc[tt], 0, 0, 0);
        }
        // bias+relu, pack n-pairs, write transpose rows (stride TROW=20 words)
#pragma unroll
        for (int tt = 0; tt < 4; ++tt) {
            float h0 = fmaxf(acc[tt][0] + b1v[tt][0], 0.f);
            float h1 = fmaxf(acc[tt][1] + b1v[tt][1], 0.f);
            float h2 = fmaxf(acc[tt][2] + b1v[tt][2], 0.f);
            float h3 = fmaxf(acc[tt][3] + b1v[tt][3], 0.f);
            T[(8 * tt + 2 * kg + 0) * TROW + edge] = pack_bf16(h0, h1);
            T[(8 * tt + 2 * kg + 1) * TROW + edge] = pack_bf16(h2, h3);
        }
        union { bf16x8 v; unsigned u[4]; } hf0, hf1;
#pragma unroll
        for (int j = 0; j < 4; ++j) {
            hf0.u[j] = T[(kg * 4 + j) * TROW + edge];
            hf1.u[j] = T[(16 + kg * 4 + j) * TROW + edge];
        }
        f32x4 o = __builtin_amdgcn_mfma_f32_16x16x32_bf16(w2f[0], hf0.v, z, 0, 0, 0);
        o = __builtin_amdgcn_mfma_f32_16x16x32_bf16(w2f[1], hf1.v, o, 0, 0, 0);

        if (tile < N_TILES) {
            float4 st = make_float4(o[0] + b2v[0], o[1] + b2v[1],
                                    o[2] + b2v[2], o[3] + b2v[3]);
            *reinterpret_cast<float4*>(e_new + (size_t)(tile * 16 + edge) * 16 + kg * 4) = st;
        }
    };

    // ---- pipeline prologue ----
    int nidA = nid_of(wtile0);
    int nidB = nid_of(wtile0 + 1);
    float4 gA0, gA1, geA0, geA1;
    load_x(nidA, gA0, gA1);
    load_e(wtile0, geA0, geA1);

    for (int i = 0; i < TILES_PER_WAVE / 2; ++i) {
        const int tA = wtile0 + 2 * i;
        const int tB = tA + 1;

        // issue B loads, then compute A
        float4 gB0, gB1, geB0, geB1;
        load_x(nidB, gB0, gB1);
        load_e(tB, geB0, geB1);
        int nidA2 = nid_of(tA + 2);
        compute(tA, T0, gA0, gA1, geA0, geA1);

        // issue A+2 loads, then compute B
        load_x(nidA2, gA0, gA1);
        load_e(tA + 2, geA0, geA1);
        nidB = nid_of(tB + 2);
        compute(tB, T1, gB0, gB1, geB0, geB1);
    }
}

// ---------------- agg: 16 threads/node, shfl_xor reduce over 4 lane-groups
__global__ __launch_bounds__(256) void agg16_kernel(
    const float* __restrict__ e_new, const unsigned* __restrict__ offs,
    const unsigned* __restrict__ elist, float* __restrict__ agg)
{
    int tid = blockIdx.x * 256 + threadIdx.x;
    int n = tid >> 4;
    int q = tid & 3;
    int r = (tid >> 2) & 3;
    unsigned lo = offs[n], hi = offs[n + 1];
    const float4* ep = reinterpret_cast<const float4*>(e_new);
    float sx = 0.f, sy = 0.f, sz = 0.f, sw = 0.f;
    for (unsigned j = lo + r; j < hi; j += 4) {
        unsigned eid = elist[j];
        float4 v = ep[(size_t)eid * 4 + q];
        sx += v.x; sy += v.y; sz += v.z; sw += v.w;
    }
    sx += __shfl_xor(sx, 4, 64); sy += __shfl_xor(sy, 4, 64);
    sz += __shfl_xor(sz, 4, 64); sw += __shfl_xor(sw, 4, 64);
    sx += __shfl_xor(sx, 8, 64); sy += __shfl_xor(sy, 8, 64);
    sz += __shfl_xor(sz, 8, 64); sw += __shfl_xor(sw, 8, 64);
    if (r == 0)
        reinterpret_cast<float4*>(agg)[(size_t)n * 4 + q] = make_float4(sx, sy, sz, sw);
}

// ---------------- node MFMA kernel: x_new = fO(concat(x, agg)), K=32 exact
__global__ __launch_bounds__(256) void node_mfma_kernel(
    const float* __restrict__ x, const float* __restrict__ agg,
    const float* __restrict__ W1, const float* __restrict__ b1,
    const float* __restrict__ W2, const float* __restrict__ b2,
    float* __restrict__ x_new)
{
    __shared__ unsigned Tld[WAVES * 2 * TBUF];
    const int lane = threadIdx.x & 63;
    const int wave = threadIdx.x >> 6;
    unsigned* T0 = Tld + wave * 2 * TBUF;
    unsigned* T1 = T0 + TBUF;
    const int nd = lane & 15;
    const int kg = lane >> 4;
    const bool lo32 = (kg < 2);
    const int h8 = kg & 1;

    bf16x8 w1f[4];
#pragma unroll
    for (int t = 0; t < 4; ++t) {
        union { bf16x8 v; unsigned u[4]; } fr;
#pragma unroll
        for (int r = 0; r < 4; ++r) {
            int k0 = kg * 8 + 2 * r;   // < 32 always
            int n  = t * 16 + nd;
            fr.u[r] = pack_bf16(W1[k0 * HID + n], W1[(k0 + 1) * HID + n]);
        }
        w1f[t] = fr.v;
    }
    bf16x8 w2f[2];
#pragma unroll
    for (int s = 0; s < 2; ++s) {
        union { bf16x8 v; unsigned u[4]; } fr;
#pragma unroll
        for (int r = 0; r < 4; ++r) {
            int k0 = s * 32 + kg * 8 + 2 * r;
            fr.u[r] = pack_bf16(W2[k0 * ED + nd], W2[(k0 + 1) * ED + nd]);
        }
        w2f[s] = fr.v;
    }
    float b1v[4][4];
#pragma unroll
    for (int t = 0; t < 4; ++t)
#pragma unroll
        for (int r = 0; r < 4; ++r) b1v[t][r] = b1[t * 16 + kg * 4 + r];
    float b2v[4];
#pragma unroll
    for (int r = 0; r < 4; ++r) b2v[r] = b2[kg * 4 + r];

    const int wtile0 = ((int)blockIdx.x * WAVES + wave) * TPW_N;
    if (wtile0 >= NT_NODE) return;

    const float4* x4 = reinterpret_cast<const float4*>(x);
    const float4* a4 = reinterpret_cast<const float4*>(agg);

    for (int t = 0; t < TPW_N; ++t) {
        int tile = wtile0 + t;
        int tc = tile < NT_NODE ? tile : NT_NODE - 1;
        int node = tc * 16 + nd;
        size_t o = (size_t)node * 4 + h8 * 2;
        float4 g0 = lo32 ? x4[o] : a4[o];
        float4 g1 = lo32 ? x4[o + 1] : a4[o + 1];

        union { bf16x8 v; unsigned u[4]; } fa;
        fa.u[0] = pack_bf16(g0.x, g0.y); fa.u[1] = pack_bf16(g0.z, g0.w);
        fa.u[2] = pack_bf16(g1.x, g1.y); fa.u[3] = pack_bf16(g1.z, g1.w);

        const f32x4 z = {0.f, 0.f, 0.f, 0.f};
        f32x4 acc[4];
#pragma unroll
        for (int tt = 0; tt < 4; ++tt)
            acc[tt] = __builtin_amdgcn_mfma_f32_16x16x32_bf16(w1f[tt], fa.v, z, 0, 0, 0);

        unsigned* T = (t & 1) ? T1 : T0;
#pragma unroll
        for (int tt = 0; tt < 4; ++tt) {
            float h0 = fmaxf(acc[tt][0] + b1v[tt][0], 0.f);
            float h1 = fmaxf(acc[tt][1] + b1v[tt][1], 0.f);
            float h2 = fmaxf(acc[tt][2] + b1v[tt][2], 0.f);
            float h3 = fmaxf(acc[tt][3] + b1v[tt][3], 0.f);
            T[(8 * tt + 2 * kg + 0) * TROW + nd] = pack_bf16(h0, h1);
            T[(8 * tt + 2 * kg + 1) * TROW + nd] = pack_bf16(h2, h3);
        }
        union { bf16x8 v; unsigned u[4]; } hf0, hf1;
#pragma unroll
        for (int j = 0; j < 4; ++j) {
            hf0.u[j] = T[(kg * 4 + j) * TROW + nd];
            hf1.u[j] = T[(16 + kg * 4 + j) * TROW + nd];
        }
        f32x4 oo = __builtin_amdgcn_mfma_f32_16x16x32_bf16(w2f[0], hf0.v, z, 0, 0, 0);
        oo = __builtin_amdgcn_mfma_f32_16x16x32_bf16(w2f[1], hf1.v, oo, 0, 0, 0);

        if (tile < NT_NODE) {
            float4 st = make_float4(oo[0] + b2v[0], oo[1] + b2v[1],
                                    oo[2] + b2v[2], oo[3] + b2v[3]);
            *reinterpret_cast<float4*>(x_new + (size_t)node * 16 + kg * 4) = st;
        }
    }
}

// ---------------- legacy fallback kernels (ws too small)
__global__ __launch_bounds__(256) void edge_kernel_atomic(
    const float* __restrict__ x, const int* __restrict__ ei,
    const float* __restrict__ e,
    const float* __restrict__ W1, const float* __restrict__ b1,
    const float* __restrict__ W2, const float* __restrict__ b2,
    float* __restrict__ e_new, float* __restrict__ agg)
{
    int idx = blockIdx.x * blockDim.x + threadIdx.x;
    if (idx >= N_EDGES) return;
    int src = ei[idx];
    int dst = ei[N_EDGES + idx];
    float m[M1];
    const float4* xd = reinterpret_cast<const float4*>(x) + dst * 4;
    const float4* xs = reinterpret_cast<const float4*>(x) + src * 4;
    const float4* ep = reinterpret_cast<const float4*>(e) + (size_t)idx * 4;
#pragma unroll
    for (int q = 0; q < 4; ++q) { float4 v = xd[q]; m[4*q]=v.x; m[4*q+1]=v.y; m[4*q+2]=v.z; m[4*q+3]=v.w; }
#pragma unroll
    for (int q = 0; q < 4; ++q) { float4 v = xs[q]; m[16+4*q]=v.x; m[16+4*q+1]=v.y; m[16+4*q+2]=v.z; m[16+4*q+3]=v.w; }
#pragma unroll
    for (int q = 0; q < 4; ++q) { float4 v = ep[q]; m[32+4*q]=v.x; m[32+4*q+1]=v.y; m[32+4*q+2]=v.z; m[32+4*q+3]=v.w; }
    float h[HID];
#pragma unroll
    for (int j = 0; j < HID; ++j) h[j] = b1[j];
#pragma unroll 4
    for (int i = 0; i < M1; ++i) {
        float mi = m[i]; const float* wr = W1 + i * HID;
#pragma unroll
        for (int j = 0; j < HID; ++j) h[j] = fmaf(mi, wr[j], h[j]);
    }
    float o[ED];
#pragma unroll
    for (int k = 0; k < ED; ++k) o[k] = b2[k];
#pragma unroll 8
    for (int j = 0; j < HID; ++j) {
        float hj = fmaxf(h[j], 0.0f); const float* wr = W2 + j * ED;
#pragma unroll
        for (int k = 0; k < ED; ++k) o[k] = fmaf(hj, wr[k], o[k]);
    }
    float4* op = reinterpret_cast<float4*>(e_new) + (size_t)idx * 4;
    op[0] = make_float4(o[0],o[1],o[2],o[3]);
    op[1] = make_float4(o[4],o[5],o[6],o[7]);
    op[2] = make_float4(o[8],o[9],o[10],o[11]);
    op[3] = make_float4(o[12],o[13],o[14],o[15]);
    float* ag = agg + (size_t)dst * ED;
#pragma unroll
    for (int k = 0; k < ED; ++k) atomicAdd(ag + k, o[k]);
}

__global__ __launch_bounds__(256) void node_kernel(
    const float* __restrict__ x, const float* __restrict__ agg,
    const float* __restrict__ W1, const float* __restrict__ b1,
    const float* __restrict__ W2, const float* __restrict__ b2,
    float* __restrict__ x_new)
{
    int idx = blockIdx.x * blockDim.x + threadIdx.x;
    if (idx >= N_NODES) return;
    float m[M2];
    const float4* xp = reinterpret_cast<const float4*>(x) + idx * 4;
    const float4* ap = reinterpret_cast<const float4*>(agg) + idx * 4;
#pragma unroll
    for (int q = 0; q < 4; ++q) { float4 v = xp[q]; m[4*q]=v.x; m[4*q+1]=v.y; m[4*q+2]=v.z; m[4*q+3]=v.w; }
#pragma unroll
    for (int q = 0; q < 4; ++q) { float4 v = ap[q]; m[16+4*q]=v.x; m[16+4*q+1]=v.y; m[16+4*q+2]=v.z; m[16+4*q+3]=v.w; }
    float h[HID];
#pragma unroll
    for (int j = 0; j < HID; ++j) h[j] = b1[j];
#pragma unroll 4
    for (int i = 0; i < M2; ++i) {
        float mi = m[i]; const float* wr = W1 + i * HID;
#pragma unroll
        for (int j = 0; j < HID; ++j) h[j] = fmaf(mi, wr[j], h[j]);
    }
    float o[ED];
#pragma unroll
    for (int k = 0; k < ED; ++k) o[k] = b2[k];
#pragma unroll 8
    for (int j = 0; j < HID; ++j) {
        float hj = fmaxf(h[j], 0.0f); const float* wr = W2 + j * ED;
#pragma unroll
        for (int k = 0; k < ED; ++k) o[k] = fmaf(hj, wr[k], o[k]);
    }
    float4* op = reinterpret_cast<float4*>(x_new) + idx * 4;
    op[0] = make_float4(o[0],o[1],o[2],o[3]);
    op[1] = make_float4(o[4],o[5],o[6],o[7]);
    op[2] = make_float4(o[8],o[9],o[10],o[11]);
    op[3] = make_float4(o[12],o[13],o[14],o[15]);
}

static inline size_t align_up(size_t v, size_t a) { return (v + a - 1) / a * a; }

extern "C" void kernel_launch(void* const* d_in, const int* in_sizes, int n_in,
                              void* d_out, int out_size, void* d_ws, size_t ws_size,
                              hipStream_t stream) {
    const float* x     = (const float*)d_in[0];
    const int*   ei    = (const int*)  d_in[1];
    const float* e     = (const float*)d_in[2];
    const float* fR_W1 = (const float*)d_in[3];
    const float* fR_b1 = (const float*)d_in[4];
    const float* fR_W2 = (const float*)d_in[5];
    const float* fR_b2 = (const float*)d_in[6];
    const float* fO_W1 = (const float*)d_in[7];
    const float* fO_b1 = (const float*)d_in[8];
    const float* fO_W2 = (const float*)d_in[9];
    const float* fO_b2 = (const float*)d_in[10];

    float* x_new = (float*)d_out;                        // [N, 16]
    float* e_new = (float*)d_out + (size_t)N_NODES * ND; // [E, 16]

    char* ws = (char*)d_ws;
    size_t o = 0;
    unsigned*      offs  = (unsigned*)(ws + o);      o += align_up((size_t)(N_NODES + 1) * 4, 256);
    unsigned*      count = (unsigned*)(ws + o);      o += align_up((size_t)N_NODES * 4, 256);
    unsigned char* slot8 = (unsigned char*)(ws + o); o += align_up((size_t)N_EDGES, 256);
    unsigned*      pw    = (unsigned*)(ws + o);      o += align_up((size_t)NB * NWORDS * 4, 256);
    unsigned*      elist = (unsigned*)(ws + o);      o += align_up((size_t)N_EDGES * 4, 256);
    unsigned*      bsum  = (unsigned*)(ws + o);      o += align_up((size_t)SCAN_NB * 4, 256);
    unsigned*      bbase = (unsigned*)(ws + o);      o += align_up((size_t)SCAN_NB * 4, 256);
    const size_t need = o;   // ~14.8 MB
    float* agg = (float*)pw; // pw (6.4MB) is dead after fill2; reuse as agg[N][16]

    if (ws_size >= need) {
        const int tiles_per_block = WAVES * TILES_PER_WAVE;  // 64
        const int nblocks = (N_TILES + tiles_per_block - 1) / tiles_per_block;
        edge_mfma_kernel<<<nblocks, 256, 0, stream>>>(
            x, ei, e, fR_W1, fR_b1, fR_W2, fR_b2, e_new);

        hist_kernel<<<NB, 1024, 0, stream>>>(ei, pw, slot8);
        bprefix_kernel<<<(NWORDS + 255) / 256, 256, 0, stream>>>(pw, count);
        scan_blocks_kernel<<<SCAN_NB, SCAN_BS, 0, stream>>>(count, offs, bsum);
        scan_bsum_kernel<<<1, 256, 0, stream>>>(bsum, bbase, offs);
        scan_add_kernel<<<SCAN_NB, SCAN_BS, 0, stream>>>(offs, bbase);
        fill2_kernel<<<NB, 1024, 0, stream>>>(ei, offs, pw, slot8, elist);

        agg16_kernel<<<(N_NODES * 16) / 256, 256, 0, stream>>>(e_new, offs, elist, agg);

        const int ntpb = WAVES * TPW_N;  // 16
        node_mfma_kernel<<<(NT_NODE + ntpb - 1) / ntpb, 256, 0, stream>>>(
            x, agg, fO_W1, fO_b1, fO_W2, fO_b2, x_new);
    } else {
        float* agg0 = (float*)d_ws;
        hipMemsetAsync(agg0, 0, (size_t)N_NODES * ED * 4, stream);
        edge_kernel_atomic<<<N_EDGES / 256, 256, 0, stream>>>(
            x, ei, e, fR_W1, fR_b1, fR_W2, fR_b2, e_new, agg0);
        node_kernel<<<(N_NODES + 255) / 256, 256, 0, stream>>>(
            x, agg0, fO_W1, fO_b1, fO_W2, fO_b2, x_new);
    }
}

// Round 10
// 187.071 us; speedup vs baseline: 3.2998x; 1.0619x over previous
//
#include <hip/hip_runtime.h>
#include <hip/hip_bf16.h>

#define N_NODES 50000
#define N_EDGES 1600000
#define ND 16
#define ED 16
#define HID 64
#define M1 (2*ND+ED)   // 48
#define M2 (ND+ED)     // 32
#define N_TILES (N_EDGES / 16)   // 100000
#define WAVES 4
#define TILES_PER_WAVE 16

// CSR-build geometry
#define NB 128
#define CHUNK (N_EDGES / NB)     // 12500
#define NWORDS (N_NODES / 4)     // 12500

// scan geometry
#define SCAN_BS 256
#define SCAN_NB ((N_NODES + SCAN_BS - 1) / SCAN_BS)   // 196

// transpose scratch: 32 rows x 20 words (stride 20 => <=2-way banks, free)
#define TROW 20
#define TBUF (32 * TROW)

// node-MLP geometry
#define NT_NODE (N_NODES / 16)   // 3125
#define TPW_N 4

typedef short bf16x8 __attribute__((ext_vector_type(8)));
typedef float f32x4  __attribute__((ext_vector_type(4)));

__device__ inline unsigned pack_bf16(float a, float b) {
    __hip_bfloat162 p = __float22bfloat162_rn(float2{a, b});
    return *reinterpret_cast<unsigned*>(&p);
}

// ---------------- hist: per-block LDS histogram (u8 x4 packed) + local slot
__global__ __launch_bounds__(1024) void hist_kernel(
    const int* __restrict__ ei,
    unsigned* __restrict__ partial_w,    // [NB][NWORDS]
    unsigned char* __restrict__ slot8)   // [E]
{
    __shared__ unsigned hist[NWORDS];
    const int b = blockIdx.x, t = threadIdx.x;
    for (int w = t; w < NWORDS; w += 1024) hist[w] = 0u;
    __syncthreads();
    const int base = b * CHUNK;
    for (int i = t; i < CHUNK; i += 1024) {
        int idx = base + i;
        int dst = ei[N_EDGES + idx];
        unsigned sh = (unsigned)(dst & 3) * 8u;
        unsigned old = atomicAdd(&hist[dst >> 2], 1u << sh);
        slot8[idx] = (unsigned char)((old >> sh) & 0xffu);
    }
    __syncthreads();
    unsigned* out = partial_w + (size_t)b * NWORDS;
    for (int w = t; w < NWORDS; w += 1024) out[w] = hist[w];
}

// ---------------- bprefix: in-place exclusive prefix over blocks per node
__global__ __launch_bounds__(256) void bprefix_kernel(
    unsigned* __restrict__ partial_w, unsigned* __restrict__ count)
{
    int w = blockIdx.x * blockDim.x + threadIdx.x;
    if (w >= NWORDS) return;
    unsigned r0 = 0, r1 = 0, r2 = 0, r3 = 0;
#pragma unroll 8
    for (int b = 0; b < NB; ++b) {
        size_t o = (size_t)b * NWORDS + w;
        unsigned v = partial_w[o];
        partial_w[o] = (r0 & 0xff) | ((r1 & 0xff) << 8) |
                       ((r2 & 0xff) << 16) | ((r3 & 0xff) << 24);
        r0 += v & 0xffu; r1 += (v >> 8) & 0xffu;
        r2 += (v >> 16) & 0xffu; r3 += (v >> 24) & 0xffu;
    }
    count[w * 4 + 0] = r0; count[w * 4 + 1] = r1;
    count[w * 4 + 2] = r2; count[w * 4 + 3] = r3;
}

// ---------------- 3-phase parallel scan: count[N] -> offs[N+1]
__global__ __launch_bounds__(SCAN_BS) void scan_blocks_kernel(
    const unsigned* __restrict__ count, unsigned* __restrict__ offs,
    unsigned* __restrict__ bsum)
{
    __shared__ unsigned s[SCAN_BS];
    const int b = blockIdx.x, t = threadIdx.x;
    const int n = b * SCAN_BS + t;
    unsigned v = (n < N_NODES) ? count[n] : 0u;
    s[t] = v;
    __syncthreads();
    for (int d = 1; d < SCAN_BS; d <<= 1) {
        unsigned u = (t >= d) ? s[t - d] : 0u;
        __syncthreads();
        s[t] += u;
        __syncthreads();
    }
    if (n < N_NODES) offs[n] = s[t] - v;
    if (t == SCAN_BS - 1) bsum[b] = s[t];
}

__global__ __launch_bounds__(256) void scan_bsum_kernel(
    const unsigned* __restrict__ bsum, unsigned* __restrict__ bbase,
    unsigned* __restrict__ offs)
{
    __shared__ unsigned s[256];
    const int t = threadIdx.x;
    unsigned v = (t < SCAN_NB) ? bsum[t] : 0u;
    s[t] = v;
    __syncthreads();
    for (int d = 1; d < 256; d <<= 1) {
        unsigned u = (t >= d) ? s[t - d] : 0u;
        __syncthreads();
        s[t] += u;
        __syncthreads();
    }
    if (t < SCAN_NB) bbase[t] = s[t] - v;
    if (t == SCAN_NB - 1) offs[N_NODES] = s[t];
}

__global__ __launch_bounds__(SCAN_BS) void scan_add_kernel(
    unsigned* __restrict__ offs, const unsigned* __restrict__ bbase)
{
    const int n = blockIdx.x * SCAN_BS + threadIdx.x;
    if (n < N_NODES) offs[n] += bbase[blockIdx.x];
}

// ---------------- fill2: elist[offs[dst] + bp[b][dst] + slot8[idx]] = idx
__global__ __launch_bounds__(1024) void fill2_kernel(
    const int* __restrict__ ei, const unsigned* __restrict__ offs,
    const unsigned* __restrict__ bp_w,
    const unsigned char* __restrict__ slot8,
    unsigned* __restrict__ elist)
{
    const int b = blockIdx.x, t = threadIdx.x;
    const int base = b * CHUNK;
    const unsigned* bpb = bp_w + (size_t)b * NWORDS;
    for (int i = t; i < CHUNK; i += 1024) {
        int idx = base + i;
        int dst = ei[N_EDGES + idx];
        unsigned pre = (bpb[dst >> 2] >> ((unsigned)(dst & 3) * 8u)) & 0xffu;
        unsigned pos = offs[dst] + pre + (unsigned)slot8[idx];
        elist[pos] = (unsigned)idx;
    }
}

// ---------------- MFMA edge kernel: swapped operands, bias-in-MFMA,
// 2-stage software pipeline: layer2(t) runs after layer1(t+1) is issued,
// so the LDS transpose write->read never serializes within a tile.
__global__ __launch_bounds__(256) void edge_mfma_kernel(
    const float* __restrict__ x, const int* __restrict__ ei,
    const float* __restrict__ e,
    const float* __restrict__ W1, const float* __restrict__ b1,
    const float* __restrict__ W2, const float* __restrict__ b2,
    float* __restrict__ e_new)
{
    __shared__ unsigned Tld[WAVES * 2 * TBUF];   // 20 KB
    const int lane = threadIdx.x & 63;
    const int wave = threadIdx.x >> 6;
    unsigned* T0 = Tld + wave * 2 * TBUF;
    unsigned* T1 = T0 + TBUF;
    const int edge = lane & 15;
    const int kg   = lane >> 4;
    const bool lo32 = (kg < 2);
    const int h8 = kg & 1;

    // ---- weight fragments; b1 folded into K=48 row of W1 fragment ----
    bf16x8 w1f[4][2];
#pragma unroll
    for (int t = 0; t < 4; ++t)
#pragma unroll
        for (int s = 0; s < 2; ++s) {
            union { bf16x8 v; unsigned u[4]; } fr;
#pragma unroll
            for (int r = 0; r < 4; ++r) {
                int k0 = s * 32 + kg * 8 + 2 * r;
                int n  = t * 16 + edge;
                float a = (k0 < M1) ? W1[k0 * HID + n] : (k0 == M1 ? b1[n] : 0.f);
                float b = (k0 + 1 < M1) ? W1[(k0 + 1) * HID + n] : 0.f;
                fr.u[r] = pack_bf16(a, b);
            }
            w1f[t][s] = fr.v;
        }
    bf16x8 w2f[2];
#pragma unroll
    for (int s = 0; s < 2; ++s) {
        union { bf16x8 v; unsigned u[4]; } fr;
#pragma unroll
        for (int r = 0; r < 4; ++r) {
            int k0 = s * 32 + kg * 8 + 2 * r;
            fr.u[r] = pack_bf16(W2[k0 * ED + edge], W2[(k0 + 1) * ED + edge]);
        }
        w2f[s] = fr.v;
    }
    float b2v[4];
#pragma unroll
    for (int r = 0; r < 4; ++r) b2v[r] = b2[kg * 4 + r];

    const int wtile0 = ((int)blockIdx.x * WAVES + wave) * TILES_PER_WAVE;
    if (wtile0 >= N_TILES) return;

    const float4* x4 = reinterpret_cast<const float4*>(x);
    const float4* e4 = reinterpret_cast<const float4*>(e);

    auto nid_of = [&](int tl) -> int {
        int tc = tl < N_TILES ? tl : N_TILES - 1;
        return ei[(lo32 ? N_EDGES : 0) + tc * 16 + edge];  // lo: dst, hi: src
    };
    auto load_x = [&](int nid, float4& a, float4& b) {
        size_t o = (size_t)nid * 4 + h8 * 2;
        a = x4[o]; b = x4[o + 1];
    };
    auto load_e = [&](int tl, float4& a, float4& b) {
        if (lo32) {
            int tc = tl < N_TILES ? tl : N_TILES - 1;
            size_t o = (size_t)(tc * 16 + edge) * 4 + kg * 2;
            a = e4[o]; b = e4[o + 1];
        } else {
            a = make_float4(0.f, 0.f, 0.f, 0.f);
            b = make_float4(0.f, 0.f, 0.f, 0.f);
        }
    };

    // layer1: global-staged B-operand, 8 MFMAs, relu, pack h -> T
    auto layer1 = [&](const float4& g0, const float4& g1,
                      const float4& ge0, const float4& ge1, unsigned* T) {
        union { bf16x8 v; unsigned u[4]; } fa, fb;
        fa.u[0] = pack_bf16(g0.x, g0.y);  fa.u[1] = pack_bf16(g0.z, g0.w);
        fa.u[2] = pack_bf16(g1.x, g1.y);  fa.u[3] = pack_bf16(g1.z, g1.w);
        fb.u[0] = pack_bf16(ge0.x, ge0.y); fb.u[1] = pack_bf16(ge0.z, ge0.w);
        fb.u[2] = pack_bf16(ge1.x, ge1.y); fb.u[3] = pack_bf16(ge1.z, ge1.w);
        if (kg == 2) fb.u[0] = 0x00003F80u;   // k=48 = 1.0 -> bias row

        const f32x4 z = {0.f, 0.f, 0.f, 0.f};
        f32x4 acc[4];
        __builtin_amdgcn_s_setprio(1);
#pragma unroll
        for (int tt = 0; tt < 4; ++tt) {
            acc[tt] = __builtin_amdgcn_mfma_f32_16x16x32_bf16(w1f[tt][0], fa.v, z, 0, 0, 0);
            acc[tt] = __builtin_amdgcn_mfma_f32_16x16x32_bf16(w1f[tt][1], fb.v, acc[tt], 0, 0, 0);
        }
        __builtin_amdgcn_s_setprio(0);
#pragma unroll
        for (int tt = 0; tt < 4; ++tt) {
            float h0 = fmaxf(acc[tt][0], 0.f);
            float h1 = fmaxf(acc[tt][1], 0.f);
            float h2 = fmaxf(acc[tt][2], 0.f);
            float h3 = fmaxf(acc[tt][3], 0.f);
            T[(8 * tt + 2 * kg + 0) * TROW + edge] = pack_bf16(h0, h1);
            T[(8 * tt + 2 * kg + 1) * TROW + edge] = pack_bf16(h2, h3);
        }
    };

    // layer2: read T (written >=1 phase ago), 2 MFMAs, coalesced store
    auto layer2 = [&](int tile, const unsigned* T) {
        union { bf16x8 v; unsigned u[4]; } hf0, hf1;
#pragma unroll
        for (int j = 0; j < 4; ++j) {
            hf0.u[j] = T[(kg * 4 + j) * TROW + edge];
            hf1.u[j] = T[(16 + kg * 4 + j) * TROW + edge];
        }
        const f32x4 z = {0.f, 0.f, 0.f, 0.f};
        f32x4 o = __builtin_amdgcn_mfma_f32_16x16x32_bf16(w2f[0], hf0.v, z, 0, 0, 0);
        o = __builtin_amdgcn_mfma_f32_16x16x32_bf16(w2f[1], hf1.v, o, 0, 0, 0);
        if (tile < N_TILES) {
            float4 st = make_float4(o[0] + b2v[0], o[1] + b2v[1],
                                    o[2] + b2v[2], o[3] + b2v[3]);
            *reinterpret_cast<float4*>(e_new + (size_t)(tile * 16 + edge) * 16 + kg * 4) = st;
        }
    };

    // ---- prologue: loads for t0,t1; ei for t2,t3 ----
    int nidA = nid_of(wtile0 + 0);
    int nidB = nid_of(wtile0 + 1);
    float4 gA0, gA1, geA0, geA1, gB0, gB1, geB0, geB1;
    load_x(nidA, gA0, gA1); load_e(wtile0 + 0, geA0, geA1);
    load_x(nidB, gB0, gB1); load_e(wtile0 + 1, geB0, geB1);
    nidA = nid_of(wtile0 + 2);
    nidB = nid_of(wtile0 + 3);

    // ---- peeled first pair: L1(t0), L1(t1), L2(t0) ----
    layer1(gA0, gA1, geA0, geA1, T0);
    load_x(nidA, gA0, gA1); load_e(wtile0 + 2, geA0, geA1);
    nidA = nid_of(wtile0 + 4);
    layer1(gB0, gB1, geB0, geB1, T1);
    load_x(nidB, gB0, gB1); load_e(wtile0 + 3, geB0, geB1);
    nidB = nid_of(wtile0 + 5);
    layer2(wtile0 + 0, T0);

    // ---- main loop: j = 1 .. 7 ----
    for (int j = 1; j < TILES_PER_WAVE / 2; ++j) {
        const int tA = wtile0 + 2 * j;
        const int tB = tA + 1;

        layer1(gA0, gA1, geA0, geA1, T0);          // L1(tA) overwrites T0 (tA-2 consumed)
        load_x(nidA, gA0, gA1); load_e(tA + 2, geA0, geA1);
        nidA = nid_of(tA + 4);
        layer2(tA - 1, T1);                        // L2(tB-1) before T1 overwritten

        layer1(gB0, gB1, geB0, geB1, T1);          // L1(tB)
        load_x(nidB, gB0, gB1); load_e(tB + 2, geB0, geB1);
        nidB = nid_of(tB + 4);
        layer2(tA, T0);                            // L2(tA), far from its T0 write
    }
    // ---- epilogue ----
    layer2(wtile0 + TILES_PER_WAVE - 1, T1);
}

// ---------------- agg: 16 threads/node, shfl_xor reduce
__global__ __launch_bounds__(256) void agg16_kernel(
    const float* __restrict__ e_new, const unsigned* __restrict__ offs,
    const unsigned* __restrict__ elist, float* __restrict__ agg)
{
    int tid = blockIdx.x * 256 + threadIdx.x;
    int n = tid >> 4;
    int q = tid & 3;
    int r = (tid >> 2) & 3;
    unsigned lo = offs[n], hi = offs[n + 1];
    const float4* ep = reinterpret_cast<const float4*>(e_new);
    float sx = 0.f, sy = 0.f, sz = 0.f, sw = 0.f;
    for (unsigned j = lo + r; j < hi; j += 4) {
        unsigned eid = elist[j];
        float4 v = ep[(size_t)eid * 4 + q];
        sx += v.x; sy += v.y; sz += v.z; sw += v.w;
    }
    sx += __shfl_xor(sx, 4, 64); sy += __shfl_xor(sy, 4, 64);
    sz += __shfl_xor(sz, 4, 64); sw += __shfl_xor(sw, 4, 64);
    sx += __shfl_xor(sx, 8, 64); sy += __shfl_xor(sy, 8, 64);
    sz += __shfl_xor(sz, 8, 64); sw += __shfl_xor(sw, 8, 64);
    if (r == 0)
        reinterpret_cast<float4*>(agg)[(size_t)n * 4 + q] = make_float4(sx, sy, sz, sw);
}

// ---------------- node MFMA kernel: x_new = fO(concat(x, agg)), K=32 exact
__global__ __launch_bounds__(256) void node_mfma_kernel(
    const float* __restrict__ x, const float* __restrict__ agg,
    const float* __restrict__ W1, const float* __restrict__ b1,
    const float* __restrict__ W2, const float* __restrict__ b2,
    float* __restrict__ x_new)
{
    __shared__ unsigned Tld[WAVES * 2 * TBUF];
    const int lane = threadIdx.x & 63;
    const int wave = threadIdx.x >> 6;
    unsigned* T0 = Tld + wave * 2 * TBUF;
    unsigned* T1 = T0 + TBUF;
    const int nd = lane & 15;
    const int kg = lane >> 4;
    const bool lo32 = (kg < 2);
    const int h8 = kg & 1;

    bf16x8 w1f[4];
#pragma unroll
    for (int t = 0; t < 4; ++t) {
        union { bf16x8 v; unsigned u[4]; } fr;
#pragma unroll
        for (int r = 0; r < 4; ++r) {
            int k0 = kg * 8 + 2 * r;
            int n  = t * 16 + nd;
            fr.u[r] = pack_bf16(W1[k0 * HID + n], W1[(k0 + 1) * HID + n]);
        }
        w1f[t] = fr.v;
    }
    bf16x8 w2f[2];
#pragma unroll
    for (int s = 0; s < 2; ++s) {
        union { bf16x8 v; unsigned u[4]; } fr;
#pragma unroll
        for (int r = 0; r < 4; ++r) {
            int k0 = s * 32 + kg * 8 + 2 * r;
            fr.u[r] = pack_bf16(W2[k0 * ED + nd], W2[(k0 + 1) * ED + nd]);
        }
        w2f[s] = fr.v;
    }
    float b1v[4][4];
#pragma unroll
    for (int t = 0; t < 4; ++t)
#pragma unroll
        for (int r = 0; r < 4; ++r) b1v[t][r] = b1[t * 16 + kg * 4 + r];
    float b2v[4];
#pragma unroll
    for (int r = 0; r < 4; ++r) b2v[r] = b2[kg * 4 + r];

    const int wtile0 = ((int)blockIdx.x * WAVES + wave) * TPW_N;
    if (wtile0 >= NT_NODE) return;

    const float4* x4 = reinterpret_cast<const float4*>(x);
    const float4* a4 = reinterpret_cast<const float4*>(agg);

    for (int t = 0; t < TPW_N; ++t) {
        int tile = wtile0 + t;
        int tc = tile < NT_NODE ? tile : NT_NODE - 1;
        int node = tc * 16 + nd;
        size_t o = (size_t)node * 4 + h8 * 2;
        float4 g0 = lo32 ? x4[o] : a4[o];
        float4 g1 = lo32 ? x4[o + 1] : a4[o + 1];

        union { bf16x8 v; unsigned u[4]; } fa;
        fa.u[0] = pack_bf16(g0.x, g0.y); fa.u[1] = pack_bf16(g0.z, g0.w);
        fa.u[2] = pack_bf16(g1.x, g1.y); fa.u[3] = pack_bf16(g1.z, g1.w);

        const f32x4 z = {0.f, 0.f, 0.f, 0.f};
        f32x4 acc[4];
#pragma unroll
        for (int tt = 0; tt < 4; ++tt)
            acc[tt] = __builtin_amdgcn_mfma_f32_16x16x32_bf16(w1f[tt], fa.v, z, 0, 0, 0);

        unsigned* T = (t & 1) ? T1 : T0;
#pragma unroll
        for (int tt = 0; tt < 4; ++tt) {
            float h0 = fmaxf(acc[tt][0] + b1v[tt][0], 0.f);
            float h1 = fmaxf(acc[tt][1] + b1v[tt][1], 0.f);
            float h2 = fmaxf(acc[tt][2] + b1v[tt][2], 0.f);
            float h3 = fmaxf(acc[tt][3] + b1v[tt][3], 0.f);
            T[(8 * tt + 2 * kg + 0) * TROW + nd] = pack_bf16(h0, h1);
            T[(8 * tt + 2 * kg + 1) * TROW + nd] = pack_bf16(h2, h3);
        }
        union { bf16x8 v; unsigned u[4]; } hf0, hf1;
#pragma unroll
        for (int j = 0; j < 4; ++j) {
            hf0.u[j] = T[(kg * 4 + j) * TROW + nd];
            hf1.u[j] = T[(16 + kg * 4 + j) * TROW + nd];
        }
        f32x4 oo = __builtin_amdgcn_mfma_f32_16x16x32_bf16(w2f[0], hf0.v, z, 0, 0, 0);
        oo = __builtin_amdgcn_mfma_f32_16x16x32_bf16(w2f[1], hf1.v, oo, 0, 0, 0);

        if (tile < NT_NODE) {
            float4 st = make_float4(oo[0] + b2v[0], oo[1] + b2v[1],
                                    oo[2] + b2v[2], oo[3] + b2v[3]);
            *reinterpret_cast<float4*>(x_new + (size_t)node * 16 + kg * 4) = st;
        }
    }
}

// ---------------- legacy fallback kernels (ws too small)
__global__ __launch_bounds__(256) void edge_kernel_atomic(
    const float* __restrict__ x, const int* __restrict__ ei,
    const float* __restrict__ e,
    const float* __restrict__ W1, const float* __restrict__ b1,
    const float* __restrict__ W2, const float* __restrict__ b2,
    float* __restrict__ e_new, float* __restrict__ agg)
{
    int idx = blockIdx.x * blockDim.x + threadIdx.x;
    if (idx >= N_EDGES) return;
    int src = ei[idx];
    int dst = ei[N_EDGES + idx];
    float m[M1];
    const float4* xd = reinterpret_cast<const float4*>(x) + dst * 4;
    const float4* xs = reinterpret_cast<const float4*>(x) + src * 4;
    const float4* ep = reinterpret_cast<const float4*>(e) + (size_t)idx * 4;
#pragma unroll
    for (int q = 0; q < 4; ++q) { float4 v = xd[q]; m[4*q]=v.x; m[4*q+1]=v.y; m[4*q+2]=v.z; m[4*q+3]=v.w; }
#pragma unroll
    for (int q = 0; q < 4; ++q) { float4 v = xs[q]; m[16+4*q]=v.x; m[16+4*q+1]=v.y; m[16+4*q+2]=v.z; m[16+4*q+3]=v.w; }
#pragma unroll
    for (int q = 0; q < 4; ++q) { float4 v = ep[q]; m[32+4*q]=v.x; m[32+4*q+1]=v.y; m[32+4*q+2]=v.z; m[32+4*q+3]=v.w; }
    float h[HID];
#pragma unroll
    for (int j = 0; j < HID; ++j) h[j] = b1[j];
#pragma unroll 4
    for (int i = 0; i < M1; ++i) {
        float mi = m[i]; const float* wr = W1 + i * HID;
#pragma unroll
        for (int j = 0; j < HID; ++j) h[j] = fmaf(mi, wr[j], h[j]);
    }
    float o[ED];
#pragma unroll
    for (int k = 0; k < ED; ++k) o[k] = b2[k];
#pragma unroll 8
    for (int j = 0; j < HID; ++j) {
        float hj = fmaxf(h[j], 0.0f); const float* wr = W2 + j * ED;
#pragma unroll
        for (int k = 0; k < ED; ++k) o[k] = fmaf(hj, wr[k], o[k]);
    }
    float4* op = reinterpret_cast<float4*>(e_new) + (size_t)idx * 4;
    op[0] = make_float4(o[0],o[1],o[2],o[3]);
    op[1] = make_float4(o[4],o[5],o[6],o[7]);
    op[2] = make_float4(o[8],o[9],o[10],o[11]);
    op[3] = make_float4(o[12],o[13],o[14],o[15]);
    float* ag = agg + (size_t)dst * ED;
#pragma unroll
    for (int k = 0; k < ED; ++k) atomicAdd(ag + k, o[k]);
}

__global__ __launch_bounds__(256) void node_kernel(
    const float* __restrict__ x, const float* __restrict__ agg,
    const float* __restrict__ W1, const float* __restrict__ b1,
    const float* __restrict__ W2, const float* __restrict__ b2,
    float* __restrict__ x_new)
{
    int idx = blockIdx.x * blockDim.x + threadIdx.x;
    if (idx >= N_NODES) return;
    float m[M2];
    const float4* xp = reinterpret_cast<const float4*>(x) + idx * 4;
    const float4* ap = reinterpret_cast<const float4*>(agg) + idx * 4;
#pragma unroll
    for (int q = 0; q < 4; ++q) { float4 v = xp[q]; m[4*q]=v.x; m[4*q+1]=v.y; m[4*q+2]=v.z; m[4*q+3]=v.w; }
#pragma unroll
    for (int q = 0; q < 4; ++q) { float4 v = ap[q]; m[16+4*q]=v.x; m[16+4*q+1]=v.y; m[16+4*q+2]=v.z; m[16+4*q+3]=v.w; }
    float h[HID];
#pragma unroll
    for (int j = 0; j < HID; ++j) h[j] = b1[j];
#pragma unroll 4
    for (int i = 0; i < M2; ++i) {
        float mi = m[i]; const float* wr = W1 + i * HID;
#pragma unroll
        for (int j = 0; j < HID; ++j) h[j] = fmaf(mi, wr[j], h[j]);
    }
    float o[ED];
#pragma unroll
    for (int k = 0; k < ED; ++k) o[k] = b2[k];
#pragma unroll 8
    for (int j = 0; j < HID; ++j) {
        float hj = fmaxf(h[j], 0.0f); const float* wr = W2 + j * ED;
#pragma unroll
        for (int k = 0; k < ED; ++k) o[k] = fmaf(hj, wr[k], o[k]);
    }
    float4* op = reinterpret_cast<float4*>(x_new) + idx * 4;
    op[0] = make_float4(o[0],o[1],o[2],o[3]);
    op[1] = make_float4(o[4],o[5],o[6],o[7]);
    op[2] = make_float4(o[8],o[9],o[10],o[11]);
    op[3] = make_float4(o[12],o[13],o[14],o[15]);
}

static inline size_t align_up(size_t v, size_t a) { return (v + a - 1) / a * a; }

extern "C" void kernel_launch(void* const* d_in, const int* in_sizes, int n_in,
                              void* d_out, int out_size, void* d_ws, size_t ws_size,
                              hipStream_t stream) {
    const float* x     = (const float*)d_in[0];
    const int*   ei    = (const int*)  d_in[1];
    const float* e     = (const float*)d_in[2];
    const float* fR_W1 = (const float*)d_in[3];
    const float* fR_b1 = (const float*)d_in[4];
    const float* fR_W2 = (const float*)d_in[5];
    const float* fR_b2 = (const float*)d_in[6];
    const float* fO_W1 = (const float*)d_in[7];
    const float* fO_b1 = (const float*)d_in[8];
    const float* fO_W2 = (const float*)d_in[9];
    const float* fO_b2 = (const float*)d_in[10];

    float* x_new = (float*)d_out;                        // [N, 16]
    float* e_new = (float*)d_out + (size_t)N_NODES * ND; // [E, 16]

    char* ws = (char*)d_ws;
    size_t o = 0;
    unsigned*      offs  = (unsigned*)(ws + o);      o += align_up((size_t)(N_NODES + 1) * 4, 256);
    unsigned*      count = (unsigned*)(ws + o);      o += align_up((size_t)N_NODES * 4, 256);
    unsigned char* slot8 = (unsigned char*)(ws + o); o += align_up((size_t)N_EDGES, 256);
    unsigned*      pw    = (unsigned*)(ws + o);      o += align_up((size_t)NB * NWORDS * 4, 256);
    unsigned*      elist = (unsigned*)(ws + o);      o += align_up((size_t)N_EDGES * 4, 256);
    unsigned*      bsum  = (unsigned*)(ws + o);      o += align_up((size_t)SCAN_NB * 4, 256);
    unsigned*      bbase = (unsigned*)(ws + o);      o += align_up((size_t)SCAN_NB * 4, 256);
    const size_t need = o;   // ~14.8 MB
    float* agg = (float*)pw; // pw dead after fill2; reuse as agg[N][16]

    if (ws_size >= need) {
        const int tiles_per_block = WAVES * TILES_PER_WAVE;  // 64
        const int nblocks = (N_TILES + tiles_per_block - 1) / tiles_per_block;
        edge_mfma_kernel<<<nblocks, 256, 0, stream>>>(
            x, ei, e, fR_W1, fR_b1, fR_W2, fR_b2, e_new);

        hist_kernel<<<NB, 1024, 0, stream>>>(ei, pw, slot8);
        bprefix_kernel<<<(NWORDS + 255) / 256, 256, 0, stream>>>(pw, count);
        scan_blocks_kernel<<<SCAN_NB, SCAN_BS, 0, stream>>>(count, offs, bsum);
        scan_bsum_kernel<<<1, 256, 0, stream>>>(bsum, bbase, offs);
        scan_add_kernel<<<SCAN_NB, SCAN_BS, 0, stream>>>(offs, bbase);
        fill2_kernel<<<NB, 1024, 0, stream>>>(ei, offs, pw, slot8, elist);

        agg16_kernel<<<(N_NODES * 16) / 256, 256, 0, stream>>>(e_new, offs, elist, agg);

        const int ntpb = WAVES * TPW_N;  // 16
        node_mfma_kernel<<<(NT_NODE + ntpb - 1) / ntpb, 256, 0, stream>>>(
            x, agg, fO_W1, fO_b1, fO_W2, fO_b2, x_new);
    } else {
        float* agg0 = (float*)d_ws;
        hipMemsetAsync(agg0, 0, (size_t)N_NODES * ED * 4, stream);
        edge_kernel_atomic<<<N_EDGES / 256, 256, 0, stream>>>(
            x, ei, e, fR_W1, fR_b1, fR_W2, fR_b2, e_new, agg0);
        node_kernel<<<(N_NODES + 255) / 256, 256, 0, stream>>>(
            x, agg0, fO_W1, fO_b1, fO_W2, fO_b2, x_new);
    }
}

// Round 11
// 186.929 us; speedup vs baseline: 3.3023x; 1.0008x over previous
//
#include <hip/hip_runtime.h>
#include <hip/hip_bf16.h>

#define N_NODES 50000
#define N_EDGES 1600000
#define ND 16
#define ED 16
#define HID 64
#define M1 (2*ND+ED)   // 48
#define M2 (ND+ED)     // 32
#define N_TILES (N_EDGES / 16)   // 100000
#define WAVES 4
#define TILES_PER_WAVE 16

// CSR-build geometry
#define NB 128
#define CHUNK (N_EDGES / NB)     // 12500
#define NWORDS (N_NODES / 4)     // 12500

// scan geometry
#define SCAN_BS 256
#define SCAN_NB ((N_NODES + SCAN_BS - 1) / SCAN_BS)   // 196

// transpose scratch: 32 rows x 20 words (stride 20 => <=2-way banks, free)
#define TROW 20
#define TBUF (32 * TROW)

// node-MLP geometry
#define NT_NODE (N_NODES / 16)   // 3125
#define TPW_N 4

typedef short bf16x8 __attribute__((ext_vector_type(8)));
typedef float f32x4  __attribute__((ext_vector_type(4)));

__device__ inline unsigned pack_bf16(float a, float b) {
    __hip_bfloat162 p = __float22bfloat162_rn(float2{a, b});
    return *reinterpret_cast<unsigned*>(&p);
}

// ---------------- xconv: x fp32 [N,16] -> bf16 [N,16] (1.6 MB, L2-resident)
__global__ __launch_bounds__(256) void xconv_kernel(
    const float* __restrict__ x, unsigned short* __restrict__ xb)
{
    int i = blockIdx.x * 256 + threadIdx.x;      // one thread per 8 elems
    if (i >= N_NODES * 2) return;
    const float4* xp = reinterpret_cast<const float4*>(x) + (size_t)i * 2;
    float4 a = xp[0], b = xp[1];
    uint4 o = make_uint4(pack_bf16(a.x, a.y), pack_bf16(a.z, a.w),
                         pack_bf16(b.x, b.y), pack_bf16(b.z, b.w));
    reinterpret_cast<uint4*>(xb)[i] = o;
}

// ---------------- hist: per-block LDS histogram (u8 x4 packed) + local slot
__global__ __launch_bounds__(1024) void hist_kernel(
    const int* __restrict__ ei,
    unsigned* __restrict__ partial_w,    // [NB][NWORDS]
    unsigned char* __restrict__ slot8)   // [E]
{
    __shared__ unsigned hist[NWORDS];
    const int b = blockIdx.x, t = threadIdx.x;
    for (int w = t; w < NWORDS; w += 1024) hist[w] = 0u;
    __syncthreads();
    const int base = b * CHUNK;
    for (int i = t; i < CHUNK; i += 1024) {
        int idx = base + i;
        int dst = ei[N_EDGES + idx];
        unsigned sh = (unsigned)(dst & 3) * 8u;
        unsigned old = atomicAdd(&hist[dst >> 2], 1u << sh);
        slot8[idx] = (unsigned char)((old >> sh) & 0xffu);
    }
    __syncthreads();
    unsigned* out = partial_w + (size_t)b * NWORDS;
    for (int w = t; w < NWORDS; w += 1024) out[w] = hist[w];
}

// ---------------- bprefix: in-place exclusive prefix over blocks per node
__global__ __launch_bounds__(256) void bprefix_kernel(
    unsigned* __restrict__ partial_w, unsigned* __restrict__ count)
{
    int w = blockIdx.x * blockDim.x + threadIdx.x;
    if (w >= NWORDS) return;
    unsigned r0 = 0, r1 = 0, r2 = 0, r3 = 0;
#pragma unroll 8
    for (int b = 0; b < NB; ++b) {
        size_t o = (size_t)b * NWORDS + w;
        unsigned v = partial_w[o];
        partial_w[o] = (r0 & 0xff) | ((r1 & 0xff) << 8) |
                       ((r2 & 0xff) << 16) | ((r3 & 0xff) << 24);
        r0 += v & 0xffu; r1 += (v >> 8) & 0xffu;
        r2 += (v >> 16) & 0xffu; r3 += (v >> 24) & 0xffu;
    }
    count[w * 4 + 0] = r0; count[w * 4 + 1] = r1;
    count[w * 4 + 2] = r2; count[w * 4 + 3] = r3;
}

// ---------------- 3-phase parallel scan: count[N] -> offs[N+1]
__global__ __launch_bounds__(SCAN_BS) void scan_blocks_kernel(
    const unsigned* __restrict__ count, unsigned* __restrict__ offs,
    unsigned* __restrict__ bsum)
{
    __shared__ unsigned s[SCAN_BS];
    const int b = blockIdx.x, t = threadIdx.x;
    const int n = b * SCAN_BS + t;
    unsigned v = (n < N_NODES) ? count[n] : 0u;
    s[t] = v;
    __syncthreads();
    for (int d = 1; d < SCAN_BS; d <<= 1) {
        unsigned u = (t >= d) ? s[t - d] : 0u;
        __syncthreads();
        s[t] += u;
        __syncthreads();
    }
    if (n < N_NODES) offs[n] = s[t] - v;
    if (t == SCAN_BS - 1) bsum[b] = s[t];
}

__global__ __launch_bounds__(256) void scan_bsum_kernel(
    const unsigned* __restrict__ bsum, unsigned* __restrict__ bbase,
    unsigned* __restrict__ offs)
{
    __shared__ unsigned s[256];
    const int t = threadIdx.x;
    unsigned v = (t < SCAN_NB) ? bsum[t] : 0u;
    s[t] = v;
    __syncthreads();
    for (int d = 1; d < 256; d <<= 1) {
        unsigned u = (t >= d) ? s[t - d] : 0u;
        __syncthreads();
        s[t] += u;
        __syncthreads();
    }
    if (t < SCAN_NB) bbase[t] = s[t] - v;
    if (t == SCAN_NB - 1) offs[N_NODES] = s[t];
}

__global__ __launch_bounds__(SCAN_BS) void scan_add_kernel(
    unsigned* __restrict__ offs, const unsigned* __restrict__ bbase)
{
    const int n = blockIdx.x * SCAN_BS + threadIdx.x;
    if (n < N_NODES) offs[n] += bbase[blockIdx.x];
}

// ---------------- fill2: elist[offs[dst] + bp[b][dst] + slot8[idx]] = idx
__global__ __launch_bounds__(1024) void fill2_kernel(
    const int* __restrict__ ei, const unsigned* __restrict__ offs,
    const unsigned* __restrict__ bp_w,
    const unsigned char* __restrict__ slot8,
    unsigned* __restrict__ elist)
{
    const int b = blockIdx.x, t = threadIdx.x;
    const int base = b * CHUNK;
    const unsigned* bpb = bp_w + (size_t)b * NWORDS;
    for (int i = t; i < CHUNK; i += 1024) {
        int idx = base + i;
        int dst = ei[N_EDGES + idx];
        unsigned pre = (bpb[dst >> 2] >> ((unsigned)(dst & 3) * 8u)) & 0xffu;
        unsigned pos = offs[dst] + pre + (unsigned)slot8[idx];
        elist[pos] = (unsigned)idx;
    }
}

// ---------------- MFMA edge kernel: bf16 x-table direct A-frag gather,
// 4-slot rotation: x/e loads issued 3-4 tiles ahead, nid (ei) 7 tiles ahead.
__global__ __launch_bounds__(256) void edge_mfma_kernel(
    const unsigned short* __restrict__ xb,  // [N,16] bf16
    const int* __restrict__ ei,
    const float* __restrict__ e,
    const float* __restrict__ W1, const float* __restrict__ b1,
    const float* __restrict__ W2, const float* __restrict__ b2,
    float* __restrict__ e_new)
{
    __shared__ unsigned Tld[WAVES * 2 * TBUF];   // 20 KB
    const int lane = threadIdx.x & 63;
    const int wave = threadIdx.x >> 6;
    unsigned* T0 = Tld + wave * 2 * TBUF;
    unsigned* T1 = T0 + TBUF;
    const int edge = lane & 15;
    const int kg   = lane >> 4;
    const bool lo32 = (kg < 2);
    const int h8 = kg & 1;

    // ---- weight fragments; b1 folded into K=48 row of W1 fragment ----
    bf16x8 w1f[4][2];
#pragma unroll
    for (int t = 0; t < 4; ++t)
#pragma unroll
        for (int s = 0; s < 2; ++s) {
            union { bf16x8 v; unsigned u[4]; } fr;
#pragma unroll
            for (int r = 0; r < 4; ++r) {
                int k0 = s * 32 + kg * 8 + 2 * r;
                int n  = t * 16 + edge;
                float a = (k0 < M1) ? W1[k0 * HID + n] : (k0 == M1 ? b1[n] : 0.f);
                float b = (k0 + 1 < M1) ? W1[(k0 + 1) * HID + n] : 0.f;
                fr.u[r] = pack_bf16(a, b);
            }
            w1f[t][s] = fr.v;
        }
    bf16x8 w2f[2];
#pragma unroll
    for (int s = 0; s < 2; ++s) {
        union { bf16x8 v; unsigned u[4]; } fr;
#pragma unroll
        for (int r = 0; r < 4; ++r) {
            int k0 = s * 32 + kg * 8 + 2 * r;
            fr.u[r] = pack_bf16(W2[k0 * ED + edge], W2[(k0 + 1) * ED + edge]);
        }
        w2f[s] = fr.v;
    }
    float b2v[4];
#pragma unroll
    for (int r = 0; r < 4; ++r) b2v[r] = b2[kg * 4 + r];

    const int wtile0 = ((int)blockIdx.x * WAVES + wave) * TILES_PER_WAVE;
    if (wtile0 >= N_TILES) return;

    const float4* e4 = reinterpret_cast<const float4*>(e);

    auto nid_of = [&](int tl) -> int {
        int tc = tl < N_TILES ? tl : N_TILES - 1;
        return ei[(lo32 ? N_EDGES : 0) + tc * 16 + edge];  // lo: dst, hi: src
    };
    auto load_fx = [&](int nid) -> bf16x8 {
        return *reinterpret_cast<const bf16x8*>(xb + (size_t)nid * 16 + h8 * 8);
    };
    auto load_e2 = [&](int tl, float4& a, float4& b) {
        if (lo32) {
            int tc = tl < N_TILES ? tl : N_TILES - 1;
            size_t o = (size_t)(tc * 16 + edge) * 4 + kg * 2;
            a = e4[o]; b = e4[o + 1];
        }
    };

    // layer1: A=W1-frag, B = [x-direct | e/bias], 8 MFMAs, relu, pack h -> T
    auto layer1 = [&](bf16x8 fx, const float4& ge0, const float4& ge1, unsigned* T) {
        union { bf16x8 v; unsigned u[4]; } fb;
        if (lo32) {
            fb.u[0] = pack_bf16(ge0.x, ge0.y); fb.u[1] = pack_bf16(ge0.z, ge0.w);
            fb.u[2] = pack_bf16(ge1.x, ge1.y); fb.u[3] = pack_bf16(ge1.z, ge1.w);
        } else {
            fb.u[0] = (kg == 2) ? 0x00003F80u : 0u;  // k=48 -> 1.0 (bias row)
            fb.u[1] = 0u; fb.u[2] = 0u; fb.u[3] = 0u;
        }

        const f32x4 z = {0.f, 0.f, 0.f, 0.f};
        f32x4 acc[4];
        __builtin_amdgcn_s_setprio(1);
#pragma unroll
        for (int tt = 0; tt < 4; ++tt) {
            acc[tt] = __builtin_amdgcn_mfma_f32_16x16x32_bf16(w1f[tt][0], fx, z, 0, 0, 0);
            acc[tt] = __builtin_amdgcn_mfma_f32_16x16x32_bf16(w1f[tt][1], fb.v, acc[tt], 0, 0, 0);
        }
        __builtin_amdgcn_s_setprio(0);
#pragma unroll
        for (int tt = 0; tt < 4; ++tt) {
            float h0 = fmaxf(acc[tt][0], 0.f);
            float h1 = fmaxf(acc[tt][1], 0.f);
            float h2 = fmaxf(acc[tt][2], 0.f);
            float h3 = fmaxf(acc[tt][3], 0.f);
            T[(8 * tt + 2 * kg + 0) * TROW + edge] = pack_bf16(h0, h1);
            T[(8 * tt + 2 * kg + 1) * TROW + edge] = pack_bf16(h2, h3);
        }
    };

    auto layer2 = [&](int tile, const unsigned* T) {
        union { bf16x8 v; unsigned u[4]; } hf0, hf1;
#pragma unroll
        for (int j = 0; j < 4; ++j) {
            hf0.u[j] = T[(kg * 4 + j) * TROW + edge];
            hf1.u[j] = T[(16 + kg * 4 + j) * TROW + edge];
        }
        const f32x4 z = {0.f, 0.f, 0.f, 0.f};
        f32x4 o = __builtin_amdgcn_mfma_f32_16x16x32_bf16(w2f[0], hf0.v, z, 0, 0, 0);
        o = __builtin_amdgcn_mfma_f32_16x16x32_bf16(w2f[1], hf1.v, o, 0, 0, 0);
        if (tile < N_TILES) {
            float4 st = make_float4(o[0] + b2v[0], o[1] + b2v[1],
                                    o[2] + b2v[2], o[3] + b2v[3]);
            *reinterpret_cast<float4*>(e_new + (size_t)(tile * 16 + edge) * 16 + kg * 4) = st;
        }
    };

    // ---- slot registers (all named; no runtime-indexed arrays) ----
    bf16x8 fxA, fxB, fxC, fxD;
    float4 geA0, geA1, geB0, geB1, geC0, geC1, geD0, geD1;

    const int t0 = wtile0;
    // prologue: nids for t0..t6; loads for t0..t2
    int m0 = nid_of(t0), m1 = nid_of(t0 + 1), m2 = nid_of(t0 + 2);
    int n3 = nid_of(t0 + 3), n4 = nid_of(t0 + 4), n5 = nid_of(t0 + 5), n6 = nid_of(t0 + 6);
    fxA = load_fx(m0); load_e2(t0 + 0, geA0, geA1);
    fxB = load_fx(m1); load_e2(t0 + 1, geB0, geB1);
    fxC = load_fx(m2); load_e2(t0 + 2, geC0, geC1);

    // peeled first group: tiles t0..t3
    fxD = load_fx(n3); load_e2(t0 + 3, geD0, geD1);
    int f0 = nid_of(t0 + 7);
    layer1(fxA, geA0, geA1, T0);
    fxA = load_fx(n4); load_e2(t0 + 4, geA0, geA1);
    int f1 = nid_of(t0 + 8);
    layer1(fxB, geB0, geB1, T1); layer2(t0 + 0, T0);
    fxB = load_fx(n5); load_e2(t0 + 5, geB0, geB1);
    int f2 = nid_of(t0 + 9);
    layer1(fxC, geC0, geC1, T0); layer2(t0 + 1, T1);
    fxC = load_fx(n6); load_e2(t0 + 6, geC0, geC1);
    int f3 = nid_of(t0 + 10);
    layer1(fxD, geD0, geD1, T1); layer2(t0 + 2, T0);
    n3 = f0; n4 = f1; n5 = f2; n6 = f3;

    // main loop: groups j=1..3 -> tiles t0+4 .. t0+15
    for (int j = 1; j < 4; ++j) {
        const int t = t0 + 4 * j;
        fxD = load_fx(n3); load_e2(t + 3, geD0, geD1);
        int g0 = nid_of(t + 7);
        layer1(fxA, geA0, geA1, T0); layer2(t - 1, T1);
        fxA = load_fx(n4); load_e2(t + 4, geA0, geA1);
        int g1 = nid_of(t + 8);
        layer1(fxB, geB0, geB1, T1); layer2(t + 0, T0);
        fxB = load_fx(n5); load_e2(t + 5, geB0, geB1);
        int g2 = nid_of(t + 9);
        layer1(fxC, geC0, geC1, T0); layer2(t + 1, T1);
        fxC = load_fx(n6); load_e2(t + 6, geC0, geC1);
        int g3 = nid_of(t + 10);
        layer1(fxD, geD0, geD1, T1); layer2(t + 2, T0);
        n3 = g0; n4 = g1; n5 = g2; n6 = g3;
    }
    layer2(t0 + 15, T1);
}

// ---------------- agg: 16 threads/node, shfl_xor reduce
__global__ __launch_bounds__(256) void agg16_kernel(
    const float* __restrict__ e_new, const unsigned* __restrict__ offs,
    const unsigned* __restrict__ elist, float* __restrict__ agg)
{
    int tid = blockIdx.x * 256 + threadIdx.x;
    int n = tid >> 4;
    int q = tid & 3;
    int r = (tid >> 2) & 3;
    unsigned lo = offs[n], hi = offs[n + 1];
    const float4* ep = reinterpret_cast<const float4*>(e_new);
    float sx = 0.f, sy = 0.f, sz = 0.f, sw = 0.f;
    for (unsigned j = lo + r; j < hi; j += 4) {
        unsigned eid = elist[j];
        float4 v = ep[(size_t)eid * 4 + q];
        sx += v.x; sy += v.y; sz += v.z; sw += v.w;
    }
    sx += __shfl_xor(sx, 4, 64); sy += __shfl_xor(sy, 4, 64);
    sz += __shfl_xor(sz, 4, 64); sw += __shfl_xor(sw, 4, 64);
    sx += __shfl_xor(sx, 8, 64); sy += __shfl_xor(sy, 8, 64);
    sz += __shfl_xor(sz, 8, 64); sw += __shfl_xor(sw, 8, 64);
    if (r == 0)
        reinterpret_cast<float4*>(agg)[(size_t)n * 4 + q] = make_float4(sx, sy, sz, sw);
}

// ---------------- node MFMA kernel: x_new = fO(concat(x, agg)), K=32 exact
__global__ __launch_bounds__(256) void node_mfma_kernel(
    const float* __restrict__ x, const float* __restrict__ agg,
    const float* __restrict__ W1, const float* __restrict__ b1,
    const float* __restrict__ W2, const float* __restrict__ b2,
    float* __restrict__ x_new)
{
    __shared__ unsigned Tld[WAVES * 2 * TBUF];
    const int lane = threadIdx.x & 63;
    const int wave = threadIdx.x >> 6;
    unsigned* T0 = Tld + wave * 2 * TBUF;
    unsigned* T1 = T0 + TBUF;
    const int nd = lane & 15;
    const int kg = lane >> 4;
    const bool lo32 = (kg < 2);
    const int h8 = kg & 1;

    bf16x8 w1f[4];
#pragma unroll
    for (int t = 0; t < 4; ++t) {
        union { bf16x8 v; unsigned u[4]; } fr;
#pragma unroll
        for (int r = 0; r < 4; ++r) {
            int k0 = kg * 8 + 2 * r;
            int n  = t * 16 + nd;
            fr.u[r] = pack_bf16(W1[k0 * HID + n], W1[(k0 + 1) * HID + n]);
        }
        w1f[t] = fr.v;
    }
    bf16x8 w2f[2];
#pragma unroll
    for (int s = 0; s < 2; ++s) {
        union { bf16x8 v; unsigned u[4]; } fr;
#pragma unroll
        for (int r = 0; r < 4; ++r) {
            int k0 = s * 32 + kg * 8 + 2 * r;
            fr.u[r] = pack_bf16(W2[k0 * ED + nd], W2[(k0 + 1) * ED + nd]);
        }
        w2f[s] = fr.v;
    }
    float b1v[4][4];
#pragma unroll
    for (int t = 0; t < 4; ++t)
#pragma unroll
        for (int r = 0; r < 4; ++r) b1v[t][r] = b1[t * 16 + kg * 4 + r];
    float b2v[4];
#pragma unroll
    for (int r = 0; r < 4; ++r) b2v[r] = b2[kg * 4 + r];

    const int wtile0 = ((int)blockIdx.x * WAVES + wave) * TPW_N;
    if (wtile0 >= NT_NODE) return;

    const float4* x4 = reinterpret_cast<const float4*>(x);
    const float4* a4 = reinterpret_cast<const float4*>(agg);

    for (int t = 0; t < TPW_N; ++t) {
        int tile = wtile0 + t;
        int tc = tile < NT_NODE ? tile : NT_NODE - 1;
        int node = tc * 16 + nd;
        size_t o = (size_t)node * 4 + h8 * 2;
        float4 g0 = lo32 ? x4[o] : a4[o];
        float4 g1 = lo32 ? x4[o + 1] : a4[o + 1];

        union { bf16x8 v; unsigned u[4]; } fa;
        fa.u[0] = pack_bf16(g0.x, g0.y); fa.u[1] = pack_bf16(g0.z, g0.w);
        fa.u[2] = pack_bf16(g1.x, g1.y); fa.u[3] = pack_bf16(g1.z, g1.w);

        const f32x4 z = {0.f, 0.f, 0.f, 0.f};
        f32x4 acc[4];
#pragma unroll
        for (int tt = 0; tt < 4; ++tt)
            acc[tt] = __builtin_amdgcn_mfma_f32_16x16x32_bf16(w1f[tt], fa.v, z, 0, 0, 0);

        unsigned* T = (t & 1) ? T1 : T0;
#pragma unroll
        for (int tt = 0; tt < 4; ++tt) {
            float h0 = fmaxf(acc[tt][0] + b1v[tt][0], 0.f);
            float h1 = fmaxf(acc[tt][1] + b1v[tt][1], 0.f);
            float h2 = fmaxf(acc[tt][2] + b1v[tt][2], 0.f);
            float h3 = fmaxf(acc[tt][3] + b1v[tt][3], 0.f);
            T[(8 * tt + 2 * kg + 0) * TROW + nd] = pack_bf16(h0, h1);
            T[(8 * tt + 2 * kg + 1) * TROW + nd] = pack_bf16(h2, h3);
        }
        union { bf16x8 v; unsigned u[4]; } hf0, hf1;
#pragma unroll
        for (int j = 0; j < 4; ++j) {
            hf0.u[j] = T[(kg * 4 + j) * TROW + nd];
            hf1.u[j] = T[(16 + kg * 4 + j) * TROW + nd];
        }
        f32x4 oo = __builtin_amdgcn_mfma_f32_16x16x32_bf16(w2f[0], hf0.v, z, 0, 0, 0);
        oo = __builtin_amdgcn_mfma_f32_16x16x32_bf16(w2f[1], hf1.v, oo, 0, 0, 0);

        if (tile < NT_NODE) {
            float4 st = make_float4(oo[0] + b2v[0], oo[1] + b2v[1],
                                    oo[2] + b2v[2], oo[3] + b2v[3]);
            *reinterpret_cast<float4*>(x_new + (size_t)node * 16 + kg * 4) = st;
        }
    }
}

// ---------------- legacy fallback kernels (ws too small)
__global__ __launch_bounds__(256) void edge_kernel_atomic(
    const float* __restrict__ x, const int* __restrict__ ei,
    const float* __restrict__ e,
    const float* __restrict__ W1, const float* __restrict__ b1,
    const float* __restrict__ W2, const float* __restrict__ b2,
    float* __restrict__ e_new, float* __restrict__ agg)
{
    int idx = blockIdx.x * blockDim.x + threadIdx.x;
    if (idx >= N_EDGES) return;
    int src = ei[idx];
    int dst = ei[N_EDGES + idx];
    float m[M1];
    const float4* xd = reinterpret_cast<const float4*>(x) + dst * 4;
    const float4* xs = reinterpret_cast<const float4*>(x) + src * 4;
    const float4* ep = reinterpret_cast<const float4*>(e) + (size_t)idx * 4;
#pragma unroll
    for (int q = 0; q < 4; ++q) { float4 v = xd[q]; m[4*q]=v.x; m[4*q+1]=v.y; m[4*q+2]=v.z; m[4*q+3]=v.w; }
#pragma unroll
    for (int q = 0; q < 4; ++q) { float4 v = xs[q]; m[16+4*q]=v.x; m[16+4*q+1]=v.y; m[16+4*q+2]=v.z; m[16+4*q+3]=v.w; }
#pragma unroll
    for (int q = 0; q < 4; ++q) { float4 v = ep[q]; m[32+4*q]=v.x; m[32+4*q+1]=v.y; m[32+4*q+2]=v.z; m[32+4*q+3]=v.w; }
    float h[HID];
#pragma unroll
    for (int j = 0; j < HID; ++j) h[j] = b1[j];
#pragma unroll 4
    for (int i = 0; i < M1; ++i) {
        float mi = m[i]; const float* wr = W1 + i * HID;
#pragma unroll
        for (int j = 0; j < HID; ++j) h[j] = fmaf(mi, wr[j], h[j]);
    }
    float o[ED];
#pragma unroll
    for (int k = 0; k < ED; ++k) o[k] = b2[k];
#pragma unroll 8
    for (int j = 0; j < HID; ++j) {
        float hj = fmaxf(h[j], 0.0f); const float* wr = W2 + j * ED;
#pragma unroll
        for (int k = 0; k < ED; ++k) o[k] = fmaf(hj, wr[k], o[k]);
    }
    float4* op = reinterpret_cast<float4*>(e_new) + (size_t)idx * 4;
    op[0] = make_float4(o[0],o[1],o[2],o[3]);
    op[1] = make_float4(o[4],o[5],o[6],o[7]);
    op[2] = make_float4(o[8],o[9],o[10],o[11]);
    op[3] = make_float4(o[12],o[13],o[14],o[15]);
    float* ag = agg + (size_t)dst * ED;
#pragma unroll
    for (int k = 0; k < ED; ++k) atomicAdd(ag + k, o[k]);
}

__global__ __launch_bounds__(256) void node_kernel(
    const float* __restrict__ x, const float* __restrict__ agg,
    const float* __restrict__ W1, const float* __restrict__ b1,
    const float* __restrict__ W2, const float* __restrict__ b2,
    float* __restrict__ x_new)
{
    int idx = blockIdx.x * blockDim.x + threadIdx.x;
    if (idx >= N_NODES) return;
    float m[M2];
    const float4* xp = reinterpret_cast<const float4*>(x) + idx * 4;
    const float4* ap = reinterpret_cast<const float4*>(agg) + idx * 4;
#pragma unroll
    for (int q = 0; q < 4; ++q) { float4 v = xp[q]; m[4*q]=v.x; m[4*q+1]=v.y; m[4*q+2]=v.z; m[4*q+3]=v.w; }
#pragma unroll
    for (int q = 0; q < 4; ++q) { float4 v = ap[q]; m[16+4*q]=v.x; m[16+4*q+1]=v.y; m[16+4*q+2]=v.z; m[16+4*q+3]=v.w; }
    float h[HID];
#pragma unroll
    for (int j = 0; j < HID; ++j) h[j] = b1[j];
#pragma unroll 4
    for (int i = 0; i < M2; ++i) {
        float mi = m[i]; const float* wr = W1 + i * HID;
#pragma unroll
        for (int j = 0; j < HID; ++j) h[j] = fmaf(mi, wr[j], h[j]);
    }
    float o[ED];
#pragma unroll
    for (int k = 0; k < ED; ++k) o[k] = b2[k];
#pragma unroll 8
    for (int j = 0; j < HID; ++j) {
        float hj = fmaxf(h[j], 0.0f); const float* wr = W2 + j * ED;
#pragma unroll
        for (int k = 0; k < ED; ++k) o[k] = fmaf(hj, wr[k], o[k]);
    }
    float4* op = reinterpret_cast<float4*>(x_new) + idx * 4;
    op[0] = make_float4(o[0],o[1],o[2],o[3]);
    op[1] = make_float4(o[4],o[5],o[6],o[7]);
    op[2] = make_float4(o[8],o[9],o[10],o[11]);
    op[3] = make_float4(o[12],o[13],o[14],o[15]);
}

static inline size_t align_up(size_t v, size_t a) { return (v + a - 1) / a * a; }

extern "C" void kernel_launch(void* const* d_in, const int* in_sizes, int n_in,
                              void* d_out, int out_size, void* d_ws, size_t ws_size,
                              hipStream_t stream) {
    const float* x     = (const float*)d_in[0];
    const int*   ei    = (const int*)  d_in[1];
    const float* e     = (const float*)d_in[2];
    const float* fR_W1 = (const float*)d_in[3];
    const float* fR_b1 = (const float*)d_in[4];
    const float* fR_W2 = (const float*)d_in[5];
    const float* fR_b2 = (const float*)d_in[6];
    const float* fO_W1 = (const float*)d_in[7];
    const float* fO_b1 = (const float*)d_in[8];
    const float* fO_W2 = (const float*)d_in[9];
    const float* fO_b2 = (const float*)d_in[10];

    float* x_new = (float*)d_out;                        // [N, 16]
    float* e_new = (float*)d_out + (size_t)N_NODES * ND; // [E, 16]

    char* ws = (char*)d_ws;
    size_t o = 0;
    unsigned*       offs  = (unsigned*)(ws + o);       o += align_up((size_t)(N_NODES + 1) * 4, 256);
    unsigned*       count = (unsigned*)(ws + o);       o += align_up((size_t)N_NODES * 4, 256);
    unsigned char*  slot8 = (unsigned char*)(ws + o);  o += align_up((size_t)N_EDGES, 256);
    unsigned*       pw    = (unsigned*)(ws + o);       o += align_up((size_t)NB * NWORDS * 4, 256);
    unsigned*       elist = (unsigned*)(ws + o);       o += align_up((size_t)N_EDGES * 4, 256);
    unsigned*       bsum  = (unsigned*)(ws + o);       o += align_up((size_t)SCAN_NB * 4, 256);
    unsigned*       bbase = (unsigned*)(ws + o);       o += align_up((size_t)SCAN_NB * 4, 256);
    unsigned short* xb    = (unsigned short*)(ws + o); o += align_up((size_t)N_NODES * ND * 2, 256);
    const size_t need = o;   // ~16.4 MB
    float* agg = (float*)pw; // pw dead after fill2; reuse as agg[N][16]

    if (ws_size >= need) {
        xconv_kernel<<<(N_NODES * 2 + 255) / 256, 256, 0, stream>>>(x, xb);

        const int tiles_per_block = WAVES * TILES_PER_WAVE;  // 64
        const int nblocks = (N_TILES + tiles_per_block - 1) / tiles_per_block;
        edge_mfma_kernel<<<nblocks, 256, 0, stream>>>(
            xb, ei, e, fR_W1, fR_b1, fR_W2, fR_b2, e_new);

        hist_kernel<<<NB, 1024, 0, stream>>>(ei, pw, slot8);
        bprefix_kernel<<<(NWORDS + 255) / 256, 256, 0, stream>>>(pw, count);
        scan_blocks_kernel<<<SCAN_NB, SCAN_BS, 0, stream>>>(count, offs, bsum);
        scan_bsum_kernel<<<1, 256, 0, stream>>>(bsum, bbase, offs);
        scan_add_kernel<<<SCAN_NB, SCAN_BS, 0, stream>>>(offs, bbase);
        fill2_kernel<<<NB, 1024, 0, stream>>>(ei, offs, pw, slot8, elist);

        agg16_kernel<<<(N_NODES * 16) / 256, 256, 0, stream>>>(e_new, offs, elist, agg);

        const int ntpb = WAVES * TPW_N;  // 16
        node_mfma_kernel<<<(NT_NODE + ntpb - 1) / ntpb, 256, 0, stream>>>(
            x, agg, fO_W1, fO_b1, fO_W2, fO_b2, x_new);
    } else {
        float* agg0 = (float*)d_ws;
        hipMemsetAsync(agg0, 0, (size_t)N_NODES * ED * 4, stream);
        edge_kernel_atomic<<<N_EDGES / 256, 256, 0, stream>>>(
            x, ei, e, fR_W1, fR_b1, fR_W2, fR_b2, e_new, agg0);
        node_kernel<<<(N_NODES + 255) / 256, 256, 0, stream>>>(
            x, agg0, fO_W1, fO_b1, fO_W2, fO_b2, x_new);
    }
}